// Round 2
// baseline (318654.468 us; speedup 1.0000x reference)
//
#include <hip/hip_runtime.h>
#include <math.h>

// ---------------------------------------------------------------------------
// GCTLN: 1M-step dopri5 integration of 3-state CTLN + linear readout.
// Round 2 (resubmit — round 1 hit GPUAcquisitionTimeout, never ran):
// exact sequential fp64 baseline (correctness anchor).
//   kernel 1: dts[i] = t_eval[i+1] - t_eval[i]   (parallel, into d_ws)
//   kernel 2: single-thread fp64 RK45 scan, writes traj (fp32) to d_out
//   kernel 3: pred = traj @ W^T + b              (parallel)
// ---------------------------------------------------------------------------

__global__ void ctln_dts(const float* __restrict__ t, float* __restrict__ dts, int n) {
  int i = blockIdx.x * blockDim.x + threadIdx.x;
  if (i < n) dts[i] = t[i + 1] - t[i];
}

// dopri5 tableau (fp64)
#define C21 (1.0/5.0)
#define C31 (3.0/40.0)
#define C32 (9.0/40.0)
#define C41 (44.0/45.0)
#define C42 (-56.0/15.0)
#define C43 (32.0/9.0)
#define C51 (19372.0/6561.0)
#define C52 (-25360.0/2187.0)
#define C53 (64448.0/6561.0)
#define C54 (-212.0/729.0)
#define C61 (9017.0/3168.0)
#define C62 (-355.0/33.0)
#define C63 (46732.0/5247.0)
#define C64 (49.0/176.0)
#define C65 (-5103.0/18656.0)
#define B1  (35.0/384.0)
#define B3  (500.0/1113.0)
#define B4  (125.0/192.0)
#define B5  (-2187.0/6784.0)
#define B6  (11.0/84.0)

// RHS: f(z)_i = -z_i + max(0, a*z_{i-1} + b*z_{i+1} + th_i)
#define RHS(zx, zy, zz, kx, ky, kz)                       \
  do {                                                    \
    double yx_ = fma(a, (zz), fma(b, (zy), th0));         \
    double yy_ = fma(a, (zx), fma(b, (zz), th1));         \
    double yz_ = fma(a, (zy), fma(b, (zx), th2));         \
    (kx) = fmax(yx_, 0.0) - (zx);                         \
    (ky) = fmax(yy_, 0.0) - (zy);                         \
    (kz) = fmax(yz_, 0.0) - (zz);                         \
  } while (0)

#define STEP(dtf, idx)                                                         \
  do {                                                                         \
    const double dt = (double)(dtf);                                           \
    double k1x,k1y,k1z,k2x,k2y,k2z,k3x,k3y,k3z;                                \
    double k4x,k4y,k4z,k5x,k5y,k5z,k6x,k6y,k6z;                                \
    double zx,zy,zz,sx,sy,sz;                                                  \
    RHS(xx, xy, xz, k1x, k1y, k1z);                                            \
    { const double d21 = dt * C21;                                             \
      zx = fma(d21,k1x,xx); zy = fma(d21,k1y,xy); zz = fma(d21,k1z,xz); }      \
    RHS(zx, zy, zz, k2x, k2y, k2z);                                            \
    sx = fma(C31,k1x, C32*k2x); sy = fma(C31,k1y, C32*k2y);                    \
    sz = fma(C31,k1z, C32*k2z);                                                \
    zx = fma(dt,sx,xx); zy = fma(dt,sy,xy); zz = fma(dt,sz,xz);                \
    RHS(zx, zy, zz, k3x, k3y, k3z);                                            \
    sx = fma(C41,k1x, fma(C42,k2x, C43*k3x));                                  \
    sy = fma(C41,k1y, fma(C42,k2y, C43*k3y));                                  \
    sz = fma(C41,k1z, fma(C42,k2z, C43*k3z));                                  \
    zx = fma(dt,sx,xx); zy = fma(dt,sy,xy); zz = fma(dt,sz,xz);                \
    RHS(zx, zy, zz, k4x, k4y, k4z);                                            \
    sx = fma(C51,k1x, fma(C52,k2x, fma(C53,k3x, C54*k4x)));                    \
    sy = fma(C51,k1y, fma(C52,k2y, fma(C53,k3y, C54*k4y)));                    \
    sz = fma(C51,k1z, fma(C52,k2z, fma(C53,k3z, C54*k4z)));                    \
    zx = fma(dt,sx,xx); zy = fma(dt,sy,xy); zz = fma(dt,sz,xz);                \
    RHS(zx, zy, zz, k5x, k5y, k5z);                                            \
    sx = fma(C61,k1x, fma(C62,k2x, fma(C63,k3x, fma(C64,k4x, C65*k5x))));      \
    sy = fma(C61,k1y, fma(C62,k2y, fma(C63,k3y, fma(C64,k4y, C65*k5y))));      \
    sz = fma(C61,k1z, fma(C62,k2z, fma(C63,k3z, fma(C64,k4z, C65*k5z))));      \
    zx = fma(dt,sx,xx); zy = fma(dt,sy,xy); zz = fma(dt,sz,xz);                \
    RHS(zx, zy, zz, k6x, k6y, k6z);                                            \
    sx = fma(B1,k1x, fma(B3,k3x, fma(B4,k4x, fma(B5,k5x, B6*k6x))));           \
    sy = fma(B1,k1y, fma(B3,k3y, fma(B4,k4y, fma(B5,k5y, B6*k6y))));           \
    sz = fma(B1,k1z, fma(B3,k3z, fma(B4,k4z, fma(B5,k5z, B6*k6z))));           \
    xx = fma(dt,sx,xx); xy = fma(dt,sy,xy); xz = fma(dt,sz,xz);                \
    traj[3*(idx)+0] = (float)xx;                                               \
    traj[3*(idx)+1] = (float)xy;                                               \
    traj[3*(idx)+2] = (float)xz;                                               \
  } while (0)

__global__ void ctln_integrate_seq(const float* __restrict__ x0f,
                                   const float* __restrict__ log_eps,
                                   const float* __restrict__ log_delta,
                                   const float* __restrict__ thf,
                                   const float* __restrict__ dts,
                                   float* __restrict__ traj, int T) {
  if (threadIdx.x != 0 || blockIdx.x != 0) return;

  const double a = -1.0 + exp((double)log_eps[0]);    // weight from i-1
  const double b = -1.0 - exp((double)log_delta[0]);  // weight from i+1
  const double th0 = (double)thf[0], th1 = (double)thf[1], th2 = (double)thf[2];

  double xx = (double)x0f[0], xy = (double)x0f[1], xz = (double)x0f[2];
  traj[0] = (float)xx; traj[1] = (float)xy; traj[2] = (float)xz;

  const int S = T - 1;             // number of steps (999999)
  const int NG = S / 8;            // full groups of 8 steps (124999)
  const float4* d4 = (const float4*)dts;

  // software-pipelined dt prefetch: group g uses quads 2g, 2g+1
  float4 A = d4[0], B = d4[1];
  const int NQ_LAST_SAFE = 2 * NG - 2;  // highest quad pair base we may touch

  for (int g = 0; g < NG; ++g) {
    const float4 cA = A, cB = B;
    int nq = 2 * g + 2;
    if (nq > NQ_LAST_SAFE) nq = 0;  // last iteration: dummy (in-range) prefetch
    A = d4[nq]; B = d4[nq + 1];

    const int base = 8 * g;
    STEP(cA.x, base + 1);
    STEP(cA.y, base + 2);
    STEP(cA.z, base + 3);
    STEP(cA.w, base + 4);
    STEP(cB.x, base + 5);
    STEP(cB.y, base + 6);
    STEP(cB.z, base + 7);
    STEP(cB.w, base + 8);
  }
  // tail steps
  for (int di = 8 * NG; di < S; ++di) {
    STEP(dts[di], di + 1);
  }
}

__global__ void ctln_readout(const float* __restrict__ traj,
                             const float* __restrict__ w,
                             const float* __restrict__ bvec,
                             float* __restrict__ pred, int T) {
  const float w00=w[0],w01=w[1],w02=w[2];
  const float w10=w[3],w11=w[4],w12=w[5];
  const float w20=w[6],w21=w[7],w22=w[8];
  const float b0=bvec[0], b1=bvec[1], b2=bvec[2];
  for (int i = blockIdx.x * blockDim.x + threadIdx.x; i < T;
       i += gridDim.x * blockDim.x) {
    const float x0 = traj[3*i], x1 = traj[3*i+1], x2 = traj[3*i+2];
    pred[3*i]   = fmaf(w00,x0, fmaf(w01,x1, fmaf(w02,x2, b0)));
    pred[3*i+1] = fmaf(w10,x0, fmaf(w11,x1, fmaf(w12,x2, b1)));
    pred[3*i+2] = fmaf(w20,x0, fmaf(w21,x1, fmaf(w22,x2, b2)));
  }
}

extern "C" void kernel_launch(void* const* d_in, const int* in_sizes, int n_in,
                              void* d_out, int out_size, void* d_ws, size_t ws_size,
                              hipStream_t stream) {
  const float* t_eval    = (const float*)d_in[0];
  const float* x0        = (const float*)d_in[1];
  const float* log_eps   = (const float*)d_in[2];
  const float* log_delta = (const float*)d_in[3];
  const float* theta     = (const float*)d_in[4];
  const float* readout_w = (const float*)d_in[5];
  const float* readout_b = (const float*)d_in[6];

  const int T = in_sizes[0];
  float* traj = (float*)d_out;
  float* pred = traj + (size_t)3 * T;
  float* dts  = (float*)d_ws;   // T-1 floats (~4 MB)

  const int nd = T - 1;
  ctln_dts<<<(nd + 255) / 256, 256, 0, stream>>>(t_eval, dts, nd);
  ctln_integrate_seq<<<1, 64, 0, stream>>>(x0, log_eps, log_delta, theta, dts, traj, T);
  ctln_readout<<<2048, 256, 0, stream>>>(traj, readout_w, readout_b, pred, T);
}

// Round 3
// 2881.562 us; speedup vs baseline: 110.5839x; 110.5839x over previous
//
#include <hip/hip_runtime.h>
#include <math.h>

// ---------------------------------------------------------------------------
// GCTLN round 3: parallel-in-time frozen-mask affine scan.
//   Given stage ReLU masks, a dopri5 step is affine: x -> A x + b (3x3 fp64).
//   coarse (seq fp32, dt=0.256) -> interp guess -> 5x { build maps from guess,
//   3-level prefix scan, re-apply from x0 } -> readout.
// d_out layout: [traj 3T][pred 3T]; pred half doubles as guess ping-pong buffer.
// ---------------------------------------------------------------------------

#define C21 (1.0/5.0)
#define C31 (3.0/40.0)
#define C32 (9.0/40.0)
#define C41 (44.0/45.0)
#define C42 (-56.0/15.0)
#define C43 (32.0/9.0)
#define C51 (19372.0/6561.0)
#define C52 (-25360.0/2187.0)
#define C53 (64448.0/6561.0)
#define C54 (-212.0/729.0)
#define C61 (9017.0/3168.0)
#define C62 (-355.0/33.0)
#define C63 (46732.0/5247.0)
#define C64 (49.0/176.0)
#define C65 (-5103.0/18656.0)
#define B1  (35.0/384.0)
#define B3  (500.0/1113.0)
#define B4  (125.0/192.0)
#define B5  (-2187.0/6784.0)
#define B6  (11.0/84.0)

struct Map { double A[9]; double b[3]; };  // x -> A x + b, A row-major

__device__ inline void map_identity(Map& m) {
#pragma unroll
  for (int i = 0; i < 9; ++i) m.A[i] = 0.0;
  m.A[0] = m.A[4] = m.A[8] = 1.0;
  m.b[0] = m.b[1] = m.b[2] = 0.0;
}

// out = m2 ∘ m1 (m1 applied first). out must not alias inputs.
__device__ inline void map_compose(Map& out, const Map& m2, const Map& m1) {
#pragma unroll
  for (int r = 0; r < 3; ++r) {
#pragma unroll
    for (int c = 0; c < 3; ++c)
      out.A[r*3+c] = m2.A[r*3+0]*m1.A[0+c] + m2.A[r*3+1]*m1.A[3+c] + m2.A[r*3+2]*m1.A[6+c];
    out.b[r] = m2.A[r*3+0]*m1.b[0] + m2.A[r*3+1]*m1.b[1] + m2.A[r*3+2]*m1.b[2] + m2.b[r];
  }
}

__device__ inline void map_apply(const Map& m, const double x[3], double y[3]) {
#pragma unroll
  for (int r = 0; r < 3; ++r)
    y[r] = m.A[r*3+0]*x[0] + m.A[r*3+1]*x[1] + m.A[r*3+2]*x[2] + m.b[r];
}

// One RHS stage. RECORD: compute gates from sign(y) and store; else use given.
template <bool RECORD>
__device__ inline void stage_k(const double z[3], const double th[3],
                               double wa, double wb, double g[3], double k[3]) {
  double y0 = fma(wa, z[2], fma(wb, z[1], th[0]));
  double y1 = fma(wa, z[0], fma(wb, z[2], th[1]));
  double y2 = fma(wa, z[1], fma(wb, z[0], th[2]));
  if (RECORD) {
    g[0] = (y0 > 0.0) ? 1.0 : 0.0;
    g[1] = (y1 > 0.0) ? 1.0 : 0.0;
    g[2] = (y2 > 0.0) ? 1.0 : 0.0;
  }
  k[0] = y0 * g[0] - z[0];
  k[1] = y1 * g[1] - z[1];
  k[2] = y2 * g[2] - z[2];
}

// Full dopri5 step evaluation with per-stage gating.
template <bool RECORD>
__device__ inline void dopri_eval(const double v[3], const double th[3], double dt,
                                  double wa, double wb, double G[6][3], double out[3]) {
  double k1[3], k2[3], k3[3], k4[3], k5[3], k6[3], z[3];
  stage_k<RECORD>(v, th, wa, wb, G[0], k1);
  const double d21 = dt * C21;
#pragma unroll
  for (int c = 0; c < 3; ++c) z[c] = fma(d21, k1[c], v[c]);
  stage_k<RECORD>(z, th, wa, wb, G[1], k2);
#pragma unroll
  for (int c = 0; c < 3; ++c) z[c] = fma(dt, fma(C31, k1[c], C32 * k2[c]), v[c]);
  stage_k<RECORD>(z, th, wa, wb, G[2], k3);
#pragma unroll
  for (int c = 0; c < 3; ++c)
    z[c] = fma(dt, fma(C41, k1[c], fma(C42, k2[c], C43 * k3[c])), v[c]);
  stage_k<RECORD>(z, th, wa, wb, G[3], k4);
#pragma unroll
  for (int c = 0; c < 3; ++c)
    z[c] = fma(dt, fma(C51, k1[c], fma(C52, k2[c], fma(C53, k3[c], C54 * k4[c]))), v[c]);
  stage_k<RECORD>(z, th, wa, wb, G[4], k5);
#pragma unroll
  for (int c = 0; c < 3; ++c)
    z[c] = fma(dt, fma(C61, k1[c], fma(C62, k2[c], fma(C63, k3[c], fma(C64, k4[c], C65 * k5[c])))), v[c]);
  stage_k<RECORD>(z, th, wa, wb, G[5], k6);
#pragma unroll
  for (int c = 0; c < 3; ++c)
    out[c] = fma(dt, fma(B1, k1[c], fma(B3, k3[c], fma(B4, k4[c], fma(B5, k5[c], B6 * k6[c])))), v[c]);
}

// Build the step's affine map from the OLD-trajectory state xo (mask source).
__device__ inline void build_map(const double xo[3], double dt, double wa, double wb,
                                 const double th[3], Map& m) {
  double G[6][3], dump[3];
  dopri_eval<true>(xo, th, dt, wa, wb, G, dump);     // numeric pass -> gates
  const double z3[3] = {0.0, 0.0, 0.0};
  dopri_eval<false>(z3, th, dt, wa, wb, G, m.b);     // b = F(0) with theta
  double e[3], col[3];
#pragma unroll
  for (int j = 0; j < 3; ++j) {
    e[0] = 0.0; e[1] = 0.0; e[2] = 0.0; e[j] = 1.0;
    dopri_eval<false>(e, z3, dt, wa, wb, G, col);    // A e_j (theta = 0)
    m.A[0 + j] = col[0];
    m.A[3 + j] = col[1];
    m.A[6 + j] = col[2];
  }
}

// ----------------------------- kernels -------------------------------------

__global__ void k_dts(const float* __restrict__ t, float* __restrict__ dts, int S) {
  int i = blockIdx.x * blockDim.x + threadIdx.x;
  if (i < S) dts[i] = t[i + 1] - t[i];
}

// sequential fp32 coarse dopri5 at fixed dtc; writes NC+1 states
__global__ void k_coarse(const float* __restrict__ x0f,
                         const float* __restrict__ le, const float* __restrict__ ld,
                         const float* __restrict__ thf,
                         float* __restrict__ cst, int NC, float dtc) {
  if (threadIdx.x != 0 || blockIdx.x != 0) return;
  const float a = -1.f + expf(le[0]);
  const float b = -1.f - expf(ld[0]);
  const float t0 = thf[0], t1 = thf[1], t2 = thf[2];
  float x = x0f[0], y = x0f[1], z = x0f[2];
  cst[0] = x; cst[1] = y; cst[2] = z;
  const float dt = dtc;
#define RHSF(px, py, pz, kx, ky, kz)                      \
  do {                                                    \
    float y0_ = fmaf(a, (pz), fmaf(b, (py), t0));         \
    float y1_ = fmaf(a, (px), fmaf(b, (pz), t1));         \
    float y2_ = fmaf(a, (py), fmaf(b, (px), t2));         \
    (kx) = fmaxf(y0_, 0.f) - (px);                        \
    (ky) = fmaxf(y1_, 0.f) - (py);                        \
    (kz) = fmaxf(y2_, 0.f) - (pz);                        \
  } while (0)
  for (int i = 1; i <= NC; ++i) {
    float k1x,k1y,k1z,k2x,k2y,k2z,k3x,k3y,k3z,k4x,k4y,k4z,k5x,k5y,k5z,k6x,k6y,k6z;
    float zx,zy,zz;
    RHSF(x, y, z, k1x, k1y, k1z);
    zx = fmaf(dt*(float)C21, k1x, x); zy = fmaf(dt*(float)C21, k1y, y); zz = fmaf(dt*(float)C21, k1z, z);
    RHSF(zx, zy, zz, k2x, k2y, k2z);
    zx = fmaf(dt, fmaf((float)C31,k1x,(float)C32*k2x), x);
    zy = fmaf(dt, fmaf((float)C31,k1y,(float)C32*k2y), y);
    zz = fmaf(dt, fmaf((float)C31,k1z,(float)C32*k2z), z);
    RHSF(zx, zy, zz, k3x, k3y, k3z);
    zx = fmaf(dt, fmaf((float)C41,k1x, fmaf((float)C42,k2x,(float)C43*k3x)), x);
    zy = fmaf(dt, fmaf((float)C41,k1y, fmaf((float)C42,k2y,(float)C43*k3y)), y);
    zz = fmaf(dt, fmaf((float)C41,k1z, fmaf((float)C42,k2z,(float)C43*k3z)), z);
    RHSF(zx, zy, zz, k4x, k4y, k4z);
    zx = fmaf(dt, fmaf((float)C51,k1x, fmaf((float)C52,k2x, fmaf((float)C53,k3x,(float)C54*k4x))), x);
    zy = fmaf(dt, fmaf((float)C51,k1y, fmaf((float)C52,k2y, fmaf((float)C53,k3y,(float)C54*k4y))), y);
    zz = fmaf(dt, fmaf((float)C51,k1z, fmaf((float)C52,k2z, fmaf((float)C53,k3z,(float)C54*k4z))), z);
    RHSF(zx, zy, zz, k5x, k5y, k5z);
    zx = fmaf(dt, fmaf((float)C61,k1x, fmaf((float)C62,k2x, fmaf((float)C63,k3x, fmaf((float)C64,k4x,(float)C65*k5x)))), x);
    zy = fmaf(dt, fmaf((float)C61,k1y, fmaf((float)C62,k2y, fmaf((float)C63,k3y, fmaf((float)C64,k4y,(float)C65*k5y)))), y);
    zz = fmaf(dt, fmaf((float)C61,k1z, fmaf((float)C62,k2z, fmaf((float)C63,k3z, fmaf((float)C64,k4z,(float)C65*k5z)))), z);
    RHSF(zx, zy, zz, k6x, k6y, k6z);
    x = fmaf(dt, fmaf((float)B1,k1x, fmaf((float)B3,k3x, fmaf((float)B4,k4x, fmaf((float)B5,k5x,(float)B6*k6x)))), x);
    y = fmaf(dt, fmaf((float)B1,k1y, fmaf((float)B3,k3y, fmaf((float)B4,k4y, fmaf((float)B5,k5y,(float)B6*k6y)))), y);
    z = fmaf(dt, fmaf((float)B1,k1z, fmaf((float)B3,k3z, fmaf((float)B4,k4z, fmaf((float)B5,k5z,(float)B6*k6z)))), z);
    cst[3*i] = x; cst[3*i+1] = y; cst[3*i+2] = z;
  }
#undef RHSF
}

// linear interp of coarse states onto the fine grid -> initial guess
__global__ void k_interp(const float* __restrict__ t_eval, const float* __restrict__ cst,
                         float* __restrict__ guess, int T, float dtc, int nstates) {
  int n = blockIdx.x * blockDim.x + threadIdx.x;
  if (n >= T) return;
  float u = t_eval[n] / dtc;
  int j = (int)u;
  if (j < 0) j = 0;
  if (j > nstates - 2) j = nstates - 2;
  float f = u - (float)j;
#pragma unroll
  for (int c = 0; c < 3; ++c) {
    float a = cst[3*j + c], b = cst[3*(j+1) + c];
    guess[3*n + c] = a + f * (b - a);
  }
}

#define L1STEPS 16

__global__ __launch_bounds__(128) void k_upsweep(
    const float* __restrict__ src, const float* __restrict__ dts,
    const float* __restrict__ le, const float* __restrict__ ld,
    const float* __restrict__ thf, Map* __restrict__ gmap, int S, int NG1) {
  int g = blockIdx.x * blockDim.x + threadIdx.x;
  if (g >= NG1) return;
  const double wa = -1.0 + exp((double)le[0]);
  const double wb = -1.0 - exp((double)ld[0]);
  const double th[3] = {(double)thf[0], (double)thf[1], (double)thf[2]};
  Map run, mp, tmp;
  map_identity(run);
  for (int s = 0; s < L1STEPS; ++s) {
    int n = g * L1STEPS + s;
    if (n >= S) break;
    double xo[3] = {(double)src[3*n], (double)src[3*n+1], (double)src[3*n+2]};
    build_map(xo, (double)dts[n], wa, wb, th, mp);
    map_compose(tmp, mp, run);
    run = tmp;
  }
  gmap[g] = run;
}

__global__ void k_l2a(const Map* __restrict__ gmap, Map* __restrict__ cmap,
                      int NG1, int CH) {
  int c = blockIdx.x * blockDim.x + threadIdx.x;
  if (c >= 256) return;
  Map run, tmp;
  map_identity(run);
  for (int j = 0; j < CH; ++j) {
    int g = c * CH + j;
    if (g >= NG1) break;
    map_compose(tmp, gmap[g], run);
    run = tmp;
  }
  cmap[c] = run;
}

__global__ __launch_bounds__(256) void k_l2b(const Map* __restrict__ cmap,
                                             Map* __restrict__ cpre) {
  __shared__ Map sm[256];
  int t = threadIdx.x;
  sm[t] = cmap[t];
  __syncthreads();
  for (int off = 1; off < 256; off <<= 1) {
    Map cur = sm[t], nb, o;
    bool doit = (t >= off);
    if (doit) nb = sm[t - off];
    __syncthreads();
    if (doit) { map_compose(o, cur, nb); sm[t] = o; }
    __syncthreads();
  }
  if (t == 0) {
    Map id; map_identity(id); cpre[0] = id;
  } else {
    cpre[t] = sm[t - 1];
  }
}

__global__ void k_l2down(const Map* __restrict__ gmap, const Map* __restrict__ cpre,
                         Map* __restrict__ gpre, int NG1, int CH) {
  int c = blockIdx.x * blockDim.x + threadIdx.x;
  if (c >= 256) return;
  Map pre = cpre[c], tmp;
  for (int j = 0; j < CH; ++j) {
    int g = c * CH + j;
    if (g >= NG1) break;
    gpre[g] = pre;
    map_compose(tmp, gmap[g], pre);
    pre = tmp;
  }
}

__global__ __launch_bounds__(128) void k_apply(
    const float* __restrict__ src, float* __restrict__ dst,
    const float* __restrict__ dts, const Map* __restrict__ gpre,
    const float* __restrict__ le, const float* __restrict__ ld,
    const float* __restrict__ thf, const float* __restrict__ x0f, int S, int NG1) {
  int g = blockIdx.x * blockDim.x + threadIdx.x;
  if (g >= NG1) return;
  const double wa = -1.0 + exp((double)le[0]);
  const double wb = -1.0 - exp((double)ld[0]);
  const double th[3] = {(double)thf[0], (double)thf[1], (double)thf[2]};
  const double x0d[3] = {(double)x0f[0], (double)x0f[1], (double)x0f[2]};
  double x[3], xn[3];
  map_apply(gpre[g], x0d, x);
  if (g == 0) { dst[0] = x0f[0]; dst[1] = x0f[1]; dst[2] = x0f[2]; }
  Map mp;
  for (int s = 0; s < L1STEPS; ++s) {
    int n = g * L1STEPS + s;
    if (n >= S) break;
    double xo[3] = {(double)src[3*n], (double)src[3*n+1], (double)src[3*n+2]};
    build_map(xo, (double)dts[n], wa, wb, th, mp);
    map_apply(mp, x, xn);
    x[0] = xn[0]; x[1] = xn[1]; x[2] = xn[2];
    dst[3*(n+1)]   = (float)x[0];
    dst[3*(n+1)+1] = (float)x[1];
    dst[3*(n+1)+2] = (float)x[2];
  }
}

__global__ void k_readout(const float* __restrict__ traj, const float* __restrict__ w,
                          const float* __restrict__ bvec, float* __restrict__ pred, int T) {
  const float w00=w[0],w01=w[1],w02=w[2];
  const float w10=w[3],w11=w[4],w12=w[5];
  const float w20=w[6],w21=w[7],w22=w[8];
  const float b0=bvec[0], b1=bvec[1], b2=bvec[2];
  for (int i = blockIdx.x * blockDim.x + threadIdx.x; i < T;
       i += gridDim.x * blockDim.x) {
    const float x0 = traj[3*i], x1 = traj[3*i+1], x2 = traj[3*i+2];
    pred[3*i]   = fmaf(w00,x0, fmaf(w01,x1, fmaf(w02,x2, b0)));
    pred[3*i+1] = fmaf(w10,x0, fmaf(w11,x1, fmaf(w12,x2, b1)));
    pred[3*i+2] = fmaf(w20,x0, fmaf(w21,x1, fmaf(w22,x2, b2)));
  }
}

// ----------------------------- launcher ------------------------------------

extern "C" void kernel_launch(void* const* d_in, const int* in_sizes, int n_in,
                              void* d_out, int out_size, void* d_ws, size_t ws_size,
                              hipStream_t stream) {
  const float* t_eval    = (const float*)d_in[0];
  const float* x0        = (const float*)d_in[1];
  const float* log_eps   = (const float*)d_in[2];
  const float* log_delta = (const float*)d_in[3];
  const float* theta     = (const float*)d_in[4];
  const float* readout_w = (const float*)d_in[5];
  const float* readout_b = (const float*)d_in[6];

  const int T  = in_sizes[0];
  const int S  = T - 1;
  const int NG1 = (S + L1STEPS - 1) / L1STEPS;
  const int CH  = (NG1 + 255) / 256;
  const float DTC = 0.256f;
  const int NC = (int)(((double)S * 1e-3) / (double)DTC) + 3;  // coarse steps
  const int NSTATES = NC + 1;

  float* trajh = (float*)d_out;
  float* predh = trajh + (size_t)3 * T;

  char* w = (char*)d_ws;
  float* dts = (float*)w;  w += (((size_t)S * 4) + 255) & ~(size_t)255;
  float* cst = (float*)w;  w += (((size_t)3 * NSTATES * 4) + 255) & ~(size_t)255;
  Map* gmap = (Map*)w;     w += (((size_t)NG1 * sizeof(Map)) + 255) & ~(size_t)255;
  Map* gpre = (Map*)w;     w += (((size_t)NG1 * sizeof(Map)) + 255) & ~(size_t)255;
  Map* cmap = (Map*)w;     w += ((256 * sizeof(Map)) + 255) & ~(size_t)255;
  Map* cpre = (Map*)w;

  k_dts<<<(S + 255) / 256, 256, 0, stream>>>(t_eval, dts, S);
  k_coarse<<<1, 64, 0, stream>>>(x0, log_eps, log_delta, theta, cst, NC, DTC);
  k_interp<<<(T + 255) / 256, 256, 0, stream>>>(t_eval, cst, predh, T, DTC, NSTATES);

  const int NITER = 5;  // odd: final apply lands in trajh
  for (int it = 0; it < NITER; ++it) {
    const float* src = (it % 2 == 0) ? predh : trajh;
    float*       dst = (it % 2 == 0) ? trajh : predh;
    k_upsweep<<<(NG1 + 127) / 128, 128, 0, stream>>>(src, dts, log_eps, log_delta,
                                                     theta, gmap, S, NG1);
    k_l2a<<<4, 64, 0, stream>>>(gmap, cmap, NG1, CH);
    k_l2b<<<1, 256, 0, stream>>>(cmap, cpre);
    k_l2down<<<4, 64, 0, stream>>>(gmap, cpre, gpre, NG1, CH);
    k_apply<<<(NG1 + 127) / 128, 128, 0, stream>>>(src, dst, dts, gpre, log_eps,
                                                   log_delta, theta, x0, S, NG1);
  }

  k_readout<<<2048, 256, 0, stream>>>(trajh, readout_w, readout_b, predh, T);
}

// Round 5
// 2019.099 us; speedup vs baseline: 157.8201x; 1.4272x over previous
//
#include <hip/hip_runtime.h>
#include <math.h>

// ---------------------------------------------------------------------------
// GCTLN round 5: 3-level parallel-in-time frozen-mask affine scan.
//   L0 seed : serial fp32 RK4, dt=0.45 (2224 steps; seed = mask guess only)
//   L1 mid  : dt=0.064 uniform grid (15625 steps), 8x single-block scan iters
//   L2 fine : t_eval grid (1e6 steps), 4x {upscan(512t/blk), bscan, apply}
//             FCH=8 steps/group -> 125k groups, 245 blocks x 8 waves (2x occ
//             vs round 3's 245 blks x 4 waves which was 1 wave/SIMD).
// d_out layout: [traj 3T][pred 3T]; guess ping-pongs between the halves.
// ---------------------------------------------------------------------------

#define C21 (1.0/5.0)
#define C31 (3.0/40.0)
#define C32 (9.0/40.0)
#define C41 (44.0/45.0)
#define C42 (-56.0/15.0)
#define C43 (32.0/9.0)
#define C51 (19372.0/6561.0)
#define C52 (-25360.0/2187.0)
#define C53 (64448.0/6561.0)
#define C54 (-212.0/729.0)
#define C61 (9017.0/3168.0)
#define C62 (-355.0/33.0)
#define C63 (46732.0/5247.0)
#define C64 (49.0/176.0)
#define C65 (-5103.0/18656.0)
#define B1  (35.0/384.0)
#define B3  (500.0/1113.0)
#define B4  (125.0/192.0)
#define B5  (-2187.0/6784.0)
#define B6  (11.0/84.0)

struct Map { double A[9]; double b[3]; };  // x -> A x + b, row-major

__device__ inline void map_identity(Map& m) {
#pragma unroll
  for (int i = 0; i < 9; ++i) m.A[i] = 0.0;
  m.A[0] = m.A[4] = m.A[8] = 1.0;
  m.b[0] = m.b[1] = m.b[2] = 0.0;
}

// out = m2 ∘ m1 (m1 applied first). out must not alias inputs.
__device__ inline void map_compose(Map& out, const Map& m2, const Map& m1) {
#pragma unroll
  for (int r = 0; r < 3; ++r) {
#pragma unroll
    for (int c = 0; c < 3; ++c)
      out.A[r*3+c] = m2.A[r*3+0]*m1.A[0+c] + m2.A[r*3+1]*m1.A[3+c] + m2.A[r*3+2]*m1.A[6+c];
    out.b[r] = m2.A[r*3+0]*m1.b[0] + m2.A[r*3+1]*m1.b[1] + m2.A[r*3+2]*m1.b[2] + m2.b[r];
  }
}

__device__ inline void map_apply(const Map& m, const double x[3], double y[3]) {
#pragma unroll
  for (int r = 0; r < 3; ++r)
    y[r] = m.A[r*3+0]*x[0] + m.A[r*3+1]*x[1] + m.A[r*3+2]*x[2] + m.b[r];
}

template <bool RECORD>
__device__ inline void stage_k(const double z[3], const double th[3],
                               double wa, double wb, double g[3], double k[3]) {
  double y0 = fma(wa, z[2], fma(wb, z[1], th[0]));
  double y1 = fma(wa, z[0], fma(wb, z[2], th[1]));
  double y2 = fma(wa, z[1], fma(wb, z[0], th[2]));
  if (RECORD) {
    g[0] = (y0 > 0.0) ? 1.0 : 0.0;
    g[1] = (y1 > 0.0) ? 1.0 : 0.0;
    g[2] = (y2 > 0.0) ? 1.0 : 0.0;
  }
  k[0] = y0 * g[0] - z[0];
  k[1] = y1 * g[1] - z[1];
  k[2] = y2 * g[2] - z[2];
}

template <bool RECORD>
__device__ inline void dopri_eval(const double v[3], const double th[3], double dt,
                                  double wa, double wb, double G[6][3], double out[3]) {
  double k1[3], k2[3], k3[3], k4[3], k5[3], k6[3], z[3];
  stage_k<RECORD>(v, th, wa, wb, G[0], k1);
  const double d21 = dt * C21;
#pragma unroll
  for (int c = 0; c < 3; ++c) z[c] = fma(d21, k1[c], v[c]);
  stage_k<RECORD>(z, th, wa, wb, G[1], k2);
#pragma unroll
  for (int c = 0; c < 3; ++c) z[c] = fma(dt, fma(C31, k1[c], C32 * k2[c]), v[c]);
  stage_k<RECORD>(z, th, wa, wb, G[2], k3);
#pragma unroll
  for (int c = 0; c < 3; ++c)
    z[c] = fma(dt, fma(C41, k1[c], fma(C42, k2[c], C43 * k3[c])), v[c]);
  stage_k<RECORD>(z, th, wa, wb, G[3], k4);
#pragma unroll
  for (int c = 0; c < 3; ++c)
    z[c] = fma(dt, fma(C51, k1[c], fma(C52, k2[c], fma(C53, k3[c], C54 * k4[c]))), v[c]);
  stage_k<RECORD>(z, th, wa, wb, G[4], k5);
#pragma unroll
  for (int c = 0; c < 3; ++c)
    z[c] = fma(dt, fma(C61, k1[c], fma(C62, k2[c], fma(C63, k3[c], fma(C64, k4[c], C65 * k5[c])))), v[c]);
  stage_k<RECORD>(z, th, wa, wb, G[5], k6);
#pragma unroll
  for (int c = 0; c < 3; ++c)
    out[c] = fma(dt, fma(B1, k1[c], fma(B3, k3[c], fma(B4, k4[c], fma(B5, k5[c], B6 * k6[c])))), v[c]);
}

__device__ inline void build_map(const double xo[3], double dt, double wa, double wb,
                                 const double th[3], Map& m) {
  double G[6][3], dump[3];
  dopri_eval<true>(xo, th, dt, wa, wb, G, dump);     // numeric pass -> gates
  const double z3[3] = {0.0, 0.0, 0.0};
  dopri_eval<false>(z3, th, dt, wa, wb, G, m.b);     // b = F(0) with theta
  double e[3], col[3];
#pragma unroll
  for (int j = 0; j < 3; ++j) {
    e[0] = 0.0; e[1] = 0.0; e[2] = 0.0; e[j] = 1.0;
    dopri_eval<false>(e, z3, dt, wa, wb, G, col);    // A e_j (theta = 0)
    m.A[0 + j] = col[0];
    m.A[3 + j] = col[1];
    m.A[6 + j] = col[2];
  }
}

// ----------------------------- kernels -------------------------------------

__global__ void k_dts(const float* __restrict__ t, float* __restrict__ dts, int S) {
  int i = blockIdx.x * blockDim.x + threadIdx.x;
  if (i < S) dts[i] = t[i + 1] - t[i];
}

// sequential fp32 RK4 seed at fixed dtc (mask-guess quality only)
__global__ void k_coarse(const float* __restrict__ x0f,
                         const float* __restrict__ le, const float* __restrict__ ld,
                         const float* __restrict__ thf,
                         float* __restrict__ cst, int NC, float dtc) {
  if (threadIdx.x != 0 || blockIdx.x != 0) return;
  const float a = -1.f + expf(le[0]);
  const float b = -1.f - expf(ld[0]);
  const float t0 = thf[0], t1 = thf[1], t2 = thf[2];
  float x = x0f[0], y = x0f[1], z = x0f[2];
  cst[0] = x; cst[1] = y; cst[2] = z;
  const float dt = dtc, dth = 0.5f * dtc, dt6 = dtc * (1.f / 6.f);
#define RHSF(px, py, pz, kx, ky, kz)                      \
  do {                                                    \
    float y0_ = fmaf(a, (pz), fmaf(b, (py), t0));         \
    float y1_ = fmaf(a, (px), fmaf(b, (pz), t1));         \
    float y2_ = fmaf(a, (py), fmaf(b, (px), t2));         \
    (kx) = fmaxf(y0_, 0.f) - (px);                        \
    (ky) = fmaxf(y1_, 0.f) - (py);                        \
    (kz) = fmaxf(y2_, 0.f) - (pz);                        \
  } while (0)
  for (int i = 1; i <= NC; ++i) {
    float k1x,k1y,k1z,k2x,k2y,k2z,k3x,k3y,k3z,k4x,k4y,k4z,zx,zy,zz;
    RHSF(x, y, z, k1x, k1y, k1z);
    zx = fmaf(dth, k1x, x); zy = fmaf(dth, k1y, y); zz = fmaf(dth, k1z, z);
    RHSF(zx, zy, zz, k2x, k2y, k2z);
    zx = fmaf(dth, k2x, x); zy = fmaf(dth, k2y, y); zz = fmaf(dth, k2z, z);
    RHSF(zx, zy, zz, k3x, k3y, k3z);
    zx = fmaf(dt, k3x, x); zy = fmaf(dt, k3y, y); zz = fmaf(dt, k3z, z);
    RHSF(zx, zy, zz, k4x, k4y, k4z);
    x = fmaf(dt6, k1x + 2.f*k2x + 2.f*k3x + k4x, x);
    y = fmaf(dt6, k1y + 2.f*k2y + 2.f*k3y + k4y, y);
    z = fmaf(dt6, k1z + 2.f*k2z + 2.f*k3z + k4z, z);
    cst[3*i] = x; cst[3*i+1] = y; cst[3*i+2] = z;
  }
#undef RHSF
}

// interp seed states (spacing dts_seed) onto the uniform mid grid (spacing dtm)
__global__ void k_interp_s2m(const float* __restrict__ seedst, float* __restrict__ mid,
                             int NMp1, float dtm, float dts_seed, int nseed_states) {
  int n = blockIdx.x * blockDim.x + threadIdx.x;
  if (n >= NMp1) return;
  float u = ((float)n * dtm) / dts_seed;
  int j = (int)u;
  if (j < 0) j = 0;
  if (j > nseed_states - 2) j = nseed_states - 2;
  float f = u - (float)j;
#pragma unroll
  for (int c = 0; c < 3; ++c) {
    float a = seedst[3*j + c], b = seedst[3*(j+1) + c];
    mid[3*n + c] = a + f * (b - a);
  }
}

// one frozen-mask Newton iteration on the uniform mid grid; single block
#define MIDT 512
__global__ __launch_bounds__(MIDT) void k_miditer(
    const float* __restrict__ src, float* __restrict__ dst,
    const float* __restrict__ le, const float* __restrict__ ld,
    const float* __restrict__ thf, const float* __restrict__ x0f,
    int NM, double dtm) {
  __shared__ Map sm[MIDT];  // 48 KiB
  const int t = threadIdx.x;
  const double wa = -1.0 + exp((double)le[0]);
  const double wb = -1.0 - exp((double)ld[0]);
  const double th[3] = {(double)thf[0], (double)thf[1], (double)thf[2]};
  const int MCH = (NM + MIDT - 1) / MIDT;

  Map run, mp, tmp;
  map_identity(run);
  for (int s = 0; s < MCH; ++s) {
    int n = t * MCH + s;
    if (n >= NM) break;
    double xo[3] = {(double)src[3*n], (double)src[3*n+1], (double)src[3*n+2]};
    build_map(xo, dtm, wa, wb, th, mp);
    map_compose(tmp, mp, run);
    run = tmp;
  }
  sm[t] = run;
  __syncthreads();
  for (int off = 1; off < MIDT; off <<= 1) {
    Map cur = sm[t], nb, o;
    bool doit = (t >= off);
    if (doit) nb = sm[t - off];
    __syncthreads();
    if (doit) { map_compose(o, cur, nb); sm[t] = o; }
    __syncthreads();
  }
  Map P;
  if (t == 0) map_identity(P); else P = sm[t - 1];  // exclusive prefix
  const double x0d[3] = {(double)x0f[0], (double)x0f[1], (double)x0f[2]};
  double x[3], xn[3];
  map_apply(P, x0d, x);
  if (t == 0) { dst[0] = x0f[0]; dst[1] = x0f[1]; dst[2] = x0f[2]; }
  for (int s = 0; s < MCH; ++s) {
    int n = t * MCH + s;
    if (n >= NM) break;
    double xo[3] = {(double)src[3*n], (double)src[3*n+1], (double)src[3*n+2]};
    build_map(xo, dtm, wa, wb, th, mp);
    map_apply(mp, x, xn);
    x[0] = xn[0]; x[1] = xn[1]; x[2] = xn[2];
    dst[3*(n+1)]   = (float)x[0];
    dst[3*(n+1)+1] = (float)x[1];
    dst[3*(n+1)+2] = (float)x[2];
  }
}

// interp mid states (uniform dtm) onto the fine t_eval grid -> guess
__global__ void k_interp_m2f(const float* __restrict__ t_eval, const float* __restrict__ mid,
                             float* __restrict__ guess, int T, float dtm, int nstates) {
  int n = blockIdx.x * blockDim.x + threadIdx.x;
  if (n >= T) return;
  float u = t_eval[n] / dtm;
  int j = (int)u;
  if (j < 0) j = 0;
  if (j > nstates - 2) j = nstates - 2;
  float f = u - (float)j;
#pragma unroll
  for (int c = 0; c < 3; ++c) {
    float a = mid[3*j + c], b = mid[3*(j+1) + c];
    guess[3*n + c] = a + f * (b - a);
  }
}

// ------------------------- fine level (3 kernels) ---------------------------

#define FT 512      // threads per upscan block (8 waves/block for occupancy)
#define FT_LOG2 9
#define FCH 8       // fine steps per group

// build group maps + in-block scan; emit local exclusive prefixes + block totals
__global__ __launch_bounds__(FT) void k_upscan(
    const float* __restrict__ src, const float* __restrict__ dts,
    const float* __restrict__ le, const float* __restrict__ ld,
    const float* __restrict__ thf,
    Map* __restrict__ lpre, Map* __restrict__ btot, int S, int NG1) {
  __shared__ Map sm[FT];  // 48 KiB
  const int t = threadIdx.x;
  const int g = blockIdx.x * FT + t;
  const double wa = -1.0 + exp((double)le[0]);
  const double wb = -1.0 - exp((double)ld[0]);
  const double th[3] = {(double)thf[0], (double)thf[1], (double)thf[2]};

  Map run, mp, tmp;
  map_identity(run);
  if (g < NG1) {
    for (int s = 0; s < FCH; ++s) {
      int n = g * FCH + s;
      if (n >= S) break;
      double xo[3] = {(double)src[3*n], (double)src[3*n+1], (double)src[3*n+2]};
      build_map(xo, (double)dts[n], wa, wb, th, mp);
      map_compose(tmp, mp, run);
      run = tmp;
    }
  }
  sm[t] = run;
  __syncthreads();
  for (int off = 1; off < FT; off <<= 1) {
    Map cur = sm[t], nb, o;
    bool doit = (t >= off);
    if (doit) nb = sm[t - off];
    __syncthreads();
    if (doit) { map_compose(o, cur, nb); sm[t] = o; }
    __syncthreads();
  }
  if (t == 0) { Map id; map_identity(id); lpre[g] = id; }
  else        { lpre[g] = sm[t - 1]; }
  if (t == FT - 1) btot[blockIdx.x] = sm[t];
}

// scan the block totals (NB <= 256); emit exclusive block prefixes
__global__ __launch_bounds__(256) void k_bscan(const Map* __restrict__ btot,
                                               Map* __restrict__ bpre, int NB) {
  __shared__ Map sm[256];
  const int t = threadIdx.x;
  if (t < NB) sm[t] = btot[t]; else map_identity(sm[t]);
  __syncthreads();
  for (int off = 1; off < 256; off <<= 1) {
    Map cur = sm[t], nb, o;
    bool doit = (t >= off);
    if (doit) nb = sm[t - off];
    __syncthreads();
    if (doit) { map_compose(o, cur, nb); sm[t] = o; }
    __syncthreads();
  }
  if (t < NB) {
    if (t == 0) { Map id; map_identity(id); bpre[0] = id; }
    else        { bpre[t] = sm[t - 1]; }
  }
}

// compose global prefix, rebuild per-step maps, emit fine states
__global__ __launch_bounds__(256) void k_apply2(
    const float* __restrict__ src, float* __restrict__ dst,
    const float* __restrict__ dts,
    const Map* __restrict__ lpre, const Map* __restrict__ bpre,
    const float* __restrict__ le, const float* __restrict__ ld,
    const float* __restrict__ thf, const float* __restrict__ x0f, int S, int NG1) {
  const int g = blockIdx.x * blockDim.x + threadIdx.x;
  if (g >= NG1) return;
  const double wa = -1.0 + exp((double)le[0]);
  const double wb = -1.0 - exp((double)ld[0]);
  const double th[3] = {(double)thf[0], (double)thf[1], (double)thf[2]};
  const double x0d[3] = {(double)x0f[0], (double)x0f[1], (double)x0f[2]};

  Map P;
  map_compose(P, lpre[g], bpre[g >> FT_LOG2]);  // block prefix applied first
  double x[3], xn[3];
  map_apply(P, x0d, x);
  if (g == 0) { dst[0] = x0f[0]; dst[1] = x0f[1]; dst[2] = x0f[2]; }
  Map mp;
  for (int s = 0; s < FCH; ++s) {
    int n = g * FCH + s;
    if (n >= S) break;
    double xo[3] = {(double)src[3*n], (double)src[3*n+1], (double)src[3*n+2]};
    build_map(xo, (double)dts[n], wa, wb, th, mp);
    map_apply(mp, x, xn);
    x[0] = xn[0]; x[1] = xn[1]; x[2] = xn[2];
    dst[3*(n+1)]   = (float)x[0];
    dst[3*(n+1)+1] = (float)x[1];
    dst[3*(n+1)+2] = (float)x[2];
  }
}

__global__ void k_readout(const float* __restrict__ traj, const float* __restrict__ w,
                          const float* __restrict__ bvec, float* __restrict__ pred, int T) {
  const float w00=w[0],w01=w[1],w02=w[2];
  const float w10=w[3],w11=w[4],w12=w[5];
  const float w20=w[6],w21=w[7],w22=w[8];
  const float b0=bvec[0], b1=bvec[1], b2=bvec[2];
  for (int i = blockIdx.x * blockDim.x + threadIdx.x; i < T;
       i += gridDim.x * blockDim.x) {
    const float x0 = traj[3*i], x1 = traj[3*i+1], x2 = traj[3*i+2];
    pred[3*i]   = fmaf(w00,x0, fmaf(w01,x1, fmaf(w02,x2, b0)));
    pred[3*i+1] = fmaf(w10,x0, fmaf(w11,x1, fmaf(w12,x2, b1)));
    pred[3*i+2] = fmaf(w20,x0, fmaf(w21,x1, fmaf(w22,x2, b2)));
  }
}

// ----------------------------- launcher ------------------------------------

extern "C" void kernel_launch(void* const* d_in, const int* in_sizes, int n_in,
                              void* d_out, int out_size, void* d_ws, size_t ws_size,
                              hipStream_t stream) {
  const float* t_eval    = (const float*)d_in[0];
  const float* x0        = (const float*)d_in[1];
  const float* log_eps   = (const float*)d_in[2];
  const float* log_delta = (const float*)d_in[3];
  const float* theta     = (const float*)d_in[4];
  const float* readout_w = (const float*)d_in[5];
  const float* readout_b = (const float*)d_in[6];

  const int T   = in_sizes[0];
  const int S   = T - 1;
  const int NG1 = (S + FCH - 1) / FCH;          // 125000 fine groups
  const int NB  = (NG1 + FT - 1) / FT;          // 245 fine blocks

  const float  DTS_SEED = 0.45f;                // well inside dopri/RK4 stability
  const int    NSEED    = (int)(((double)S * 1e-3) / (double)DTS_SEED) + 2;  // 2224
  const double DTM      = 0.064;
  const int    NM       = (int)(((double)S * 1e-3) / DTM) + 1;               // 15625

  float* trajh = (float*)d_out;
  float* predh = trajh + (size_t)3 * T;

  char* w = (char*)d_ws;
  float* dts    = (float*)w;  w += (((size_t)S * 4) + 255) & ~(size_t)255;
  float* seedst = (float*)w;  w += (((size_t)3 * (NSEED + 1) * 4) + 255) & ~(size_t)255;
  float* midA   = (float*)w;  w += (((size_t)3 * (NM + 1) * 4) + 255) & ~(size_t)255;
  float* midB   = (float*)w;  w += (((size_t)3 * (NM + 1) * 4) + 255) & ~(size_t)255;
  Map* lpre     = (Map*)w;    w += (((size_t)NB * FT * sizeof(Map)) + 255) & ~(size_t)255;
  Map* btot     = (Map*)w;    w += ((256 * sizeof(Map)) + 255) & ~(size_t)255;
  Map* bpre     = (Map*)w;

  k_dts<<<(S + 255) / 256, 256, 0, stream>>>(t_eval, dts, S);
  k_coarse<<<1, 64, 0, stream>>>(x0, log_eps, log_delta, theta, seedst, NSEED, DTS_SEED);
  k_interp_s2m<<<(NM + 1 + 255) / 256, 256, 0, stream>>>(seedst, midA, NM + 1,
                                                         (float)DTM, DTS_SEED, NSEED + 1);
  // 8 mid Newton iterations (ping-pong, even count: final lands back in midA)
  for (int it = 0; it < 8; ++it) {
    const float* s = (it % 2 == 0) ? midA : midB;
    float*       d = (it % 2 == 0) ? midB : midA;
    k_miditer<<<1, MIDT, 0, stream>>>(s, d, log_eps, log_delta, theta, x0, NM, DTM);
  }

  // guess -> trajh; 4 fine iterations (even count: final lands in trajh)
  k_interp_m2f<<<(T + 255) / 256, 256, 0, stream>>>(t_eval, midA, trajh, T,
                                                    (float)DTM, NM + 1);
  const int NITER = 4;
  for (int it = 0; it < NITER; ++it) {
    const float* src = (it % 2 == 0) ? trajh : predh;
    float*       dst = (it % 2 == 0) ? predh : trajh;
    k_upscan<<<NB, FT, 0, stream>>>(src, dts, log_eps, log_delta, theta, lpre, btot, S, NG1);
    k_bscan<<<1, 256, 0, stream>>>(btot, bpre, NB);
    k_apply2<<<(NG1 + 255) / 256, 256, 0, stream>>>(src, dst, dts, lpre, bpre,
                                                    log_eps, log_delta, theta, x0, S, NG1);
  }

  k_readout<<<2048, 256, 0, stream>>>(trajh, readout_w, readout_b, predh, T);
}

// Round 6
// 1704.457 us; speedup vs baseline: 186.9536x; 1.1846x over previous
//
#include <hip/hip_runtime.h>
#include <math.h>

// ---------------------------------------------------------------------------
// GCTLN round 6: 3-level frozen-mask affine scan, mixed precision.
//   L0 seed : serial fp32 RK4, dt=0.45 (unchanged, proven)
//   L1 mid  : dt=0.064 grid, 8x single-block scan iters  -> fp32
//   L2 fine : t_eval grid, 3 iters: 2x fp32 + final fp64
// Theory: fp64 scan kernels spill VGPRs (Map+G+k state ~200 doubles, 256-reg
// cap at 512-thread blocks); fp32 halves live state -> no spill + 2x ALU.
// Only the final iteration must be fp64 (masks tolerate 1e-4 guess error).
// d_out layout: [traj 3T][pred 3T]; guess ping-pongs between halves.
// ---------------------------------------------------------------------------

#define C21 (1.0/5.0)
#define C31 (3.0/40.0)
#define C32 (9.0/40.0)
#define C41 (44.0/45.0)
#define C42 (-56.0/15.0)
#define C43 (32.0/9.0)
#define C51 (19372.0/6561.0)
#define C52 (-25360.0/2187.0)
#define C53 (64448.0/6561.0)
#define C54 (-212.0/729.0)
#define C61 (9017.0/3168.0)
#define C62 (-355.0/33.0)
#define C63 (46732.0/5247.0)
#define C64 (49.0/176.0)
#define C65 (-5103.0/18656.0)
#define B1  (35.0/384.0)
#define B3  (500.0/1113.0)
#define B4  (125.0/192.0)
#define B5  (-2187.0/6784.0)
#define B6  (11.0/84.0)

template <typename T> struct MapT { T A[9]; T b[3]; };  // x -> A x + b

template <typename T>
__device__ inline void map_identity(MapT<T>& m) {
#pragma unroll
  for (int i = 0; i < 9; ++i) m.A[i] = T(0);
  m.A[0] = m.A[4] = m.A[8] = T(1);
  m.b[0] = m.b[1] = m.b[2] = T(0);
}

// out = m2 ∘ m1 (m1 applied first). out must not alias inputs.
template <typename T>
__device__ inline void map_compose(MapT<T>& out, const MapT<T>& m2, const MapT<T>& m1) {
#pragma unroll
  for (int r = 0; r < 3; ++r) {
#pragma unroll
    for (int c = 0; c < 3; ++c)
      out.A[r*3+c] = m2.A[r*3+0]*m1.A[0+c] + m2.A[r*3+1]*m1.A[3+c] + m2.A[r*3+2]*m1.A[6+c];
    out.b[r] = m2.A[r*3+0]*m1.b[0] + m2.A[r*3+1]*m1.b[1] + m2.A[r*3+2]*m1.b[2] + m2.b[r];
  }
}

template <typename T>
__device__ inline void map_apply(const MapT<T>& m, const T x[3], T y[3]) {
#pragma unroll
  for (int r = 0; r < 3; ++r)
    y[r] = m.A[r*3+0]*x[0] + m.A[r*3+1]*x[1] + m.A[r*3+2]*x[2] + m.b[r];
}

template <typename T, bool RECORD>
__device__ inline void stage_k(const T z[3], const T th[3],
                               T wa, T wb, T g[3], T k[3]) {
  T y0 = fma(wa, z[2], fma(wb, z[1], th[0]));
  T y1 = fma(wa, z[0], fma(wb, z[2], th[1]));
  T y2 = fma(wa, z[1], fma(wb, z[0], th[2]));
  if (RECORD) {
    g[0] = (y0 > T(0)) ? T(1) : T(0);
    g[1] = (y1 > T(0)) ? T(1) : T(0);
    g[2] = (y2 > T(0)) ? T(1) : T(0);
  }
  k[0] = y0 * g[0] - z[0];
  k[1] = y1 * g[1] - z[1];
  k[2] = y2 * g[2] - z[2];
}

template <typename T, bool RECORD>
__device__ inline void dopri_eval(const T v[3], const T th[3], T dt,
                                  T wa, T wb, T G[6][3], T out[3]) {
  T k1[3], k2[3], k3[3], k4[3], k5[3], k6[3], z[3];
  stage_k<T, RECORD>(v, th, wa, wb, G[0], k1);
  const T d21 = dt * T(C21);
#pragma unroll
  for (int c = 0; c < 3; ++c) z[c] = fma(d21, k1[c], v[c]);
  stage_k<T, RECORD>(z, th, wa, wb, G[1], k2);
#pragma unroll
  for (int c = 0; c < 3; ++c) z[c] = fma(dt, fma(T(C31), k1[c], T(C32) * k2[c]), v[c]);
  stage_k<T, RECORD>(z, th, wa, wb, G[2], k3);
#pragma unroll
  for (int c = 0; c < 3; ++c)
    z[c] = fma(dt, fma(T(C41), k1[c], fma(T(C42), k2[c], T(C43) * k3[c])), v[c]);
  stage_k<T, RECORD>(z, th, wa, wb, G[3], k4);
#pragma unroll
  for (int c = 0; c < 3; ++c)
    z[c] = fma(dt, fma(T(C51), k1[c], fma(T(C52), k2[c], fma(T(C53), k3[c], T(C54) * k4[c]))), v[c]);
  stage_k<T, RECORD>(z, th, wa, wb, G[4], k5);
#pragma unroll
  for (int c = 0; c < 3; ++c)
    z[c] = fma(dt, fma(T(C61), k1[c], fma(T(C62), k2[c], fma(T(C63), k3[c], fma(T(C64), k4[c], T(C65) * k5[c])))), v[c]);
  stage_k<T, RECORD>(z, th, wa, wb, G[5], k6);
#pragma unroll
  for (int c = 0; c < 3; ++c)
    out[c] = fma(dt, fma(T(B1), k1[c], fma(T(B3), k3[c], fma(T(B4), k4[c], fma(T(B5), k5[c], T(B6) * k6[c])))), v[c]);
}

template <typename T>
__device__ inline void build_map(const T xo[3], T dt, T wa, T wb,
                                 const T th[3], MapT<T>& m) {
  T G[6][3], dump[3];
  dopri_eval<T, true>(xo, th, dt, wa, wb, G, dump);   // numeric pass -> gates
  const T z3[3] = {T(0), T(0), T(0)};
  dopri_eval<T, false>(z3, th, dt, wa, wb, G, m.b);   // b = F(0) with theta
  T e[3], col[3];
#pragma unroll
  for (int j = 0; j < 3; ++j) {
    e[0] = T(0); e[1] = T(0); e[2] = T(0); e[j] = T(1);
    dopri_eval<T, false>(e, z3, dt, wa, wb, G, col);  // A e_j (theta = 0)
    m.A[0 + j] = col[0];
    m.A[3 + j] = col[1];
    m.A[6 + j] = col[2];
  }
}

// ----------------------------- kernels -------------------------------------

__global__ void k_dts(const float* __restrict__ t, float* __restrict__ dts, int S) {
  int i = blockIdx.x * blockDim.x + threadIdx.x;
  if (i < S) dts[i] = t[i + 1] - t[i];
}

// sequential fp32 RK4 seed at fixed dtc (mask-guess quality only)
__global__ void k_coarse(const float* __restrict__ x0f,
                         const float* __restrict__ le, const float* __restrict__ ld,
                         const float* __restrict__ thf,
                         float* __restrict__ cst, int NC, float dtc) {
  if (threadIdx.x != 0 || blockIdx.x != 0) return;
  const float a = -1.f + expf(le[0]);
  const float b = -1.f - expf(ld[0]);
  const float t0 = thf[0], t1 = thf[1], t2 = thf[2];
  float x = x0f[0], y = x0f[1], z = x0f[2];
  cst[0] = x; cst[1] = y; cst[2] = z;
  const float dt = dtc, dth = 0.5f * dtc, dt6 = dtc * (1.f / 6.f);
#define RHSF(px, py, pz, kx, ky, kz)                      \
  do {                                                    \
    float y0_ = fmaf(a, (pz), fmaf(b, (py), t0));         \
    float y1_ = fmaf(a, (px), fmaf(b, (pz), t1));         \
    float y2_ = fmaf(a, (py), fmaf(b, (px), t2));         \
    (kx) = fmaxf(y0_, 0.f) - (px);                        \
    (ky) = fmaxf(y1_, 0.f) - (py);                        \
    (kz) = fmaxf(y2_, 0.f) - (pz);                        \
  } while (0)
  for (int i = 1; i <= NC; ++i) {
    float k1x,k1y,k1z,k2x,k2y,k2z,k3x,k3y,k3z,k4x,k4y,k4z,zx,zy,zz;
    RHSF(x, y, z, k1x, k1y, k1z);
    zx = fmaf(dth, k1x, x); zy = fmaf(dth, k1y, y); zz = fmaf(dth, k1z, z);
    RHSF(zx, zy, zz, k2x, k2y, k2z);
    zx = fmaf(dth, k2x, x); zy = fmaf(dth, k2y, y); zz = fmaf(dth, k2z, z);
    RHSF(zx, zy, zz, k3x, k3y, k3z);
    zx = fmaf(dt, k3x, x); zy = fmaf(dt, k3y, y); zz = fmaf(dt, k3z, z);
    RHSF(zx, zy, zz, k4x, k4y, k4z);
    x = fmaf(dt6, k1x + 2.f*k2x + 2.f*k3x + k4x, x);
    y = fmaf(dt6, k1y + 2.f*k2y + 2.f*k3y + k4y, y);
    z = fmaf(dt6, k1z + 2.f*k2z + 2.f*k3z + k4z, z);
    cst[3*i] = x; cst[3*i+1] = y; cst[3*i+2] = z;
  }
#undef RHSF
}

// interp seed states (spacing dts_seed) onto the uniform mid grid (spacing dtm)
__global__ void k_interp_s2m(const float* __restrict__ seedst, float* __restrict__ mid,
                             int NMp1, float dtm, float dts_seed, int nseed_states) {
  int n = blockIdx.x * blockDim.x + threadIdx.x;
  if (n >= NMp1) return;
  float u = ((float)n * dtm) / dts_seed;
  int j = (int)u;
  if (j < 0) j = 0;
  if (j > nseed_states - 2) j = nseed_states - 2;
  float f = u - (float)j;
#pragma unroll
  for (int c = 0; c < 3; ++c) {
    float a = seedst[3*j + c], b = seedst[3*(j+1) + c];
    mid[3*n + c] = a + f * (b - a);
  }
}

// one frozen-mask Newton iteration on the uniform mid grid; single block
#define MIDT 512
template <typename T>
__global__ __launch_bounds__(MIDT) void k_miditer(
    const float* __restrict__ src, float* __restrict__ dst,
    const float* __restrict__ le, const float* __restrict__ ld,
    const float* __restrict__ thf, const float* __restrict__ x0f,
    int NM, double dtm) {
  __shared__ MapT<T> sm[MIDT];
  const int t = threadIdx.x;
  const T wa = (T)(-1.0 + exp((double)le[0]));
  const T wb = (T)(-1.0 - exp((double)ld[0]));
  const T th[3] = {(T)thf[0], (T)thf[1], (T)thf[2]};
  const T dtmT = (T)dtm;
  const int MCH = (NM + MIDT - 1) / MIDT;

  MapT<T> run, mp, tmp;
  map_identity(run);
  for (int s = 0; s < MCH; ++s) {
    int n = t * MCH + s;
    if (n >= NM) break;
    T xo[3] = {(T)src[3*n], (T)src[3*n+1], (T)src[3*n+2]};
    build_map(xo, dtmT, wa, wb, th, mp);
    map_compose(tmp, mp, run);
    run = tmp;
  }
  sm[t] = run;
  __syncthreads();
  for (int off = 1; off < MIDT; off <<= 1) {
    MapT<T> cur = sm[t], nb, o;
    bool doit = (t >= off);
    if (doit) nb = sm[t - off];
    __syncthreads();
    if (doit) { map_compose(o, cur, nb); sm[t] = o; }
    __syncthreads();
  }
  MapT<T> P;
  if (t == 0) map_identity(P); else P = sm[t - 1];  // exclusive prefix
  const T x0d[3] = {(T)x0f[0], (T)x0f[1], (T)x0f[2]};
  T x[3], xn[3];
  map_apply(P, x0d, x);
  if (t == 0) { dst[0] = x0f[0]; dst[1] = x0f[1]; dst[2] = x0f[2]; }
  for (int s = 0; s < MCH; ++s) {
    int n = t * MCH + s;
    if (n >= NM) break;
    T xo[3] = {(T)src[3*n], (T)src[3*n+1], (T)src[3*n+2]};
    build_map(xo, dtmT, wa, wb, th, mp);
    map_apply(mp, x, xn);
    x[0] = xn[0]; x[1] = xn[1]; x[2] = xn[2];
    dst[3*(n+1)]   = (float)x[0];
    dst[3*(n+1)+1] = (float)x[1];
    dst[3*(n+1)+2] = (float)x[2];
  }
}

// interp mid states (uniform dtm) onto the fine t_eval grid -> guess
__global__ void k_interp_m2f(const float* __restrict__ t_eval, const float* __restrict__ mid,
                             float* __restrict__ guess, int T, float dtm, int nstates) {
  int n = blockIdx.x * blockDim.x + threadIdx.x;
  if (n >= T) return;
  float u = t_eval[n] / dtm;
  int j = (int)u;
  if (j < 0) j = 0;
  if (j > nstates - 2) j = nstates - 2;
  float f = u - (float)j;
#pragma unroll
  for (int c = 0; c < 3; ++c) {
    float a = mid[3*j + c], b = mid[3*(j+1) + c];
    guess[3*n + c] = a + f * (b - a);
  }
}

// ------------------------- fine level (3 kernels) ---------------------------

#define FT 512      // threads per upscan block
#define FT_LOG2 9
#define FCH 8       // fine steps per group

// build group maps + in-block scan; emit local exclusive prefixes + block totals
template <typename T>
__global__ __launch_bounds__(FT) void k_upscan(
    const float* __restrict__ src, const float* __restrict__ dts,
    const float* __restrict__ le, const float* __restrict__ ld,
    const float* __restrict__ thf,
    MapT<T>* __restrict__ lpre, MapT<T>* __restrict__ btot, int S, int NG1) {
  __shared__ MapT<T> sm[FT];
  const int t = threadIdx.x;
  const int g = blockIdx.x * FT + t;
  const T wa = (T)(-1.0 + exp((double)le[0]));
  const T wb = (T)(-1.0 - exp((double)ld[0]));
  const T th[3] = {(T)thf[0], (T)thf[1], (T)thf[2]};

  MapT<T> run, mp, tmp;
  map_identity(run);
  if (g < NG1) {
    for (int s = 0; s < FCH; ++s) {
      int n = g * FCH + s;
      if (n >= S) break;
      T xo[3] = {(T)src[3*n], (T)src[3*n+1], (T)src[3*n+2]};
      build_map(xo, (T)dts[n], wa, wb, th, mp);
      map_compose(tmp, mp, run);
      run = tmp;
    }
  }
  sm[t] = run;
  __syncthreads();
  for (int off = 1; off < FT; off <<= 1) {
    MapT<T> cur = sm[t], nb, o;
    bool doit = (t >= off);
    if (doit) nb = sm[t - off];
    __syncthreads();
    if (doit) { map_compose(o, cur, nb); sm[t] = o; }
    __syncthreads();
  }
  if (t == 0) { MapT<T> id; map_identity(id); lpre[g] = id; }
  else        { lpre[g] = sm[t - 1]; }
  if (t == FT - 1) btot[blockIdx.x] = sm[t];
}

// scan the block totals (NB <= 256); emit exclusive block prefixes
template <typename T>
__global__ __launch_bounds__(256) void k_bscan(const MapT<T>* __restrict__ btot,
                                               MapT<T>* __restrict__ bpre, int NB) {
  __shared__ MapT<T> sm[256];
  const int t = threadIdx.x;
  if (t < NB) sm[t] = btot[t]; else map_identity(sm[t]);
  __syncthreads();
  for (int off = 1; off < 256; off <<= 1) {
    MapT<T> cur = sm[t], nb, o;
    bool doit = (t >= off);
    if (doit) nb = sm[t - off];
    __syncthreads();
    if (doit) { map_compose(o, cur, nb); sm[t] = o; }
    __syncthreads();
  }
  if (t < NB) {
    if (t == 0) { MapT<T> id; map_identity(id); bpre[0] = id; }
    else        { bpre[t] = sm[t - 1]; }
  }
}

// compose global prefix, rebuild per-step maps, emit fine states
template <typename T>
__global__ __launch_bounds__(256) void k_apply2(
    const float* __restrict__ src, float* __restrict__ dst,
    const float* __restrict__ dts,
    const MapT<T>* __restrict__ lpre, const MapT<T>* __restrict__ bpre,
    const float* __restrict__ le, const float* __restrict__ ld,
    const float* __restrict__ thf, const float* __restrict__ x0f, int S, int NG1) {
  const int g = blockIdx.x * blockDim.x + threadIdx.x;
  if (g >= NG1) return;
  const T wa = (T)(-1.0 + exp((double)le[0]));
  const T wb = (T)(-1.0 - exp((double)ld[0]));
  const T th[3] = {(T)thf[0], (T)thf[1], (T)thf[2]};
  const T x0d[3] = {(T)x0f[0], (T)x0f[1], (T)x0f[2]};

  MapT<T> P;
  map_compose(P, lpre[g], bpre[g >> FT_LOG2]);  // block prefix applied first
  T x[3], xn[3];
  map_apply(P, x0d, x);
  if (g == 0) { dst[0] = x0f[0]; dst[1] = x0f[1]; dst[2] = x0f[2]; }
  MapT<T> mp;
  for (int s = 0; s < FCH; ++s) {
    int n = g * FCH + s;
    if (n >= S) break;
    T xo[3] = {(T)src[3*n], (T)src[3*n+1], (T)src[3*n+2]};
    build_map(xo, (T)dts[n], wa, wb, th, mp);
    map_apply(mp, x, xn);
    x[0] = xn[0]; x[1] = xn[1]; x[2] = xn[2];
    dst[3*(n+1)]   = (float)x[0];
    dst[3*(n+1)+1] = (float)x[1];
    dst[3*(n+1)+2] = (float)x[2];
  }
}

__global__ void k_readout(const float* __restrict__ traj, const float* __restrict__ w,
                          const float* __restrict__ bvec, float* __restrict__ pred, int T) {
  const float w00=w[0],w01=w[1],w02=w[2];
  const float w10=w[3],w11=w[4],w12=w[5];
  const float w20=w[6],w21=w[7],w22=w[8];
  const float b0=bvec[0], b1=bvec[1], b2=bvec[2];
  for (int i = blockIdx.x * blockDim.x + threadIdx.x; i < T;
       i += gridDim.x * blockDim.x) {
    const float x0 = traj[3*i], x1 = traj[3*i+1], x2 = traj[3*i+2];
    pred[3*i]   = fmaf(w00,x0, fmaf(w01,x1, fmaf(w02,x2, b0)));
    pred[3*i+1] = fmaf(w10,x0, fmaf(w11,x1, fmaf(w12,x2, b1)));
    pred[3*i+2] = fmaf(w20,x0, fmaf(w21,x1, fmaf(w22,x2, b2)));
  }
}

// ----------------------------- launcher ------------------------------------

extern "C" void kernel_launch(void* const* d_in, const int* in_sizes, int n_in,
                              void* d_out, int out_size, void* d_ws, size_t ws_size,
                              hipStream_t stream) {
  const float* t_eval    = (const float*)d_in[0];
  const float* x0        = (const float*)d_in[1];
  const float* log_eps   = (const float*)d_in[2];
  const float* log_delta = (const float*)d_in[3];
  const float* theta     = (const float*)d_in[4];
  const float* readout_w = (const float*)d_in[5];
  const float* readout_b = (const float*)d_in[6];

  const int T   = in_sizes[0];
  const int S   = T - 1;
  const int NG1 = (S + FCH - 1) / FCH;          // 125000 fine groups
  const int NB  = (NG1 + FT - 1) / FT;          // 245 fine blocks

  const float  DTS_SEED = 0.45f;
  const int    NSEED    = (int)(((double)S * 1e-3) / (double)DTS_SEED) + 2;  // 2224
  const double DTM      = 0.064;
  const int    NM       = (int)(((double)S * 1e-3) / DTM) + 1;               // 15625

  float* trajh = (float*)d_out;
  float* predh = trajh + (size_t)3 * T;

  // workspace sized for the fp64 (largest) Map variants; fp32 reuses same slots
  char* w = (char*)d_ws;
  float* dts    = (float*)w;  w += (((size_t)S * 4) + 255) & ~(size_t)255;
  float* seedst = (float*)w;  w += (((size_t)3 * (NSEED + 1) * 4) + 255) & ~(size_t)255;
  float* midA   = (float*)w;  w += (((size_t)3 * (NM + 1) * 4) + 255) & ~(size_t)255;
  float* midB   = (float*)w;  w += (((size_t)3 * (NM + 1) * 4) + 255) & ~(size_t)255;
  void* lpre_v  = (void*)w;   w += (((size_t)NB * FT * sizeof(MapT<double>)) + 255) & ~(size_t)255;
  void* btot_v  = (void*)w;   w += ((256 * sizeof(MapT<double>)) + 255) & ~(size_t)255;
  void* bpre_v  = (void*)w;

  k_dts<<<(S + 255) / 256, 256, 0, stream>>>(t_eval, dts, S);
  k_coarse<<<1, 64, 0, stream>>>(x0, log_eps, log_delta, theta, seedst, NSEED, DTS_SEED);
  k_interp_s2m<<<(NM + 1 + 255) / 256, 256, 0, stream>>>(seedst, midA, NM + 1,
                                                         (float)DTM, DTS_SEED, NSEED + 1);
  // 8 fp32 mid Newton iterations (even count: final lands back in midA)
  for (int it = 0; it < 8; ++it) {
    const float* s = (it % 2 == 0) ? midA : midB;
    float*       d = (it % 2 == 0) ? midB : midA;
    k_miditer<float><<<1, MIDT, 0, stream>>>(s, d, log_eps, log_delta, theta, x0, NM, DTM);
  }

  // guess -> predh; fine: it0 fp32 predh->trajh, it1 fp32 trajh->predh,
  // it2 fp64 predh->trajh (final, full precision)
  k_interp_m2f<<<(T + 255) / 256, 256, 0, stream>>>(t_eval, midA, predh, T,
                                                    (float)DTM, NM + 1);
  for (int it = 0; it < 2; ++it) {
    const float* src = (it % 2 == 0) ? predh : trajh;
    float*       dst = (it % 2 == 0) ? trajh : predh;
    MapT<float>* lpre = (MapT<float>*)lpre_v;
    MapT<float>* btot = (MapT<float>*)btot_v;
    MapT<float>* bpre = (MapT<float>*)bpre_v;
    k_upscan<float><<<NB, FT, 0, stream>>>(src, dts, log_eps, log_delta, theta,
                                           lpre, btot, S, NG1);
    k_bscan<float><<<1, 256, 0, stream>>>(btot, bpre, NB);
    k_apply2<float><<<(NG1 + 255) / 256, 256, 0, stream>>>(src, dst, dts, lpre, bpre,
                                                           log_eps, log_delta, theta,
                                                           x0, S, NG1);
  }
  {
    MapT<double>* lpre = (MapT<double>*)lpre_v;
    MapT<double>* btot = (MapT<double>*)btot_v;
    MapT<double>* bpre = (MapT<double>*)bpre_v;
    k_upscan<double><<<NB, FT, 0, stream>>>(predh, dts, log_eps, log_delta, theta,
                                            lpre, btot, S, NG1);
    k_bscan<double><<<1, 256, 0, stream>>>(btot, bpre, NB);
    k_apply2<double><<<(NG1 + 255) / 256, 256, 0, stream>>>(predh, trajh, dts, lpre, bpre,
                                                            log_eps, log_delta, theta,
                                                            x0, S, NG1);
  }

  k_readout<<<2048, 256, 0, stream>>>(trajh, readout_w, readout_b, predh, T);
}

// Round 7
// 1686.220 us; speedup vs baseline: 188.9756x; 1.0108x over previous
//
#include <hip/hip_runtime.h>
#include <math.h>

// ---------------------------------------------------------------------------
// GCTLN round 7: frozen-mask affine scan; wave-shuffle (register) Map scans.
//   L0 seed : serial fp32 RK4, dt=0.45 (unchanged, proven)
//   L1 mid  : dt=0.064 grid, 8x single-block iters, fp32, shfl-scan
//   L2 fine : t_eval grid, 2 iters (1x fp32 + 1x fp64), shfl-scan
// Change vs r6: LDS Hillis-Steele (18 barriers, ~1MB LDS traffic/block)
// -> per-wave __shfl_up scan in registers + tiny wave-total LDS array.
// d_out layout: [traj 3T][pred 3T]; guess ping-pongs between halves.
// ---------------------------------------------------------------------------

#define C21 (1.0/5.0)
#define C31 (3.0/40.0)
#define C32 (9.0/40.0)
#define C41 (44.0/45.0)
#define C42 (-56.0/15.0)
#define C43 (32.0/9.0)
#define C51 (19372.0/6561.0)
#define C52 (-25360.0/2187.0)
#define C53 (64448.0/6561.0)
#define C54 (-212.0/729.0)
#define C61 (9017.0/3168.0)
#define C62 (-355.0/33.0)
#define C63 (46732.0/5247.0)
#define C64 (49.0/176.0)
#define C65 (-5103.0/18656.0)
#define B1  (35.0/384.0)
#define B3  (500.0/1113.0)
#define B4  (125.0/192.0)
#define B5  (-2187.0/6784.0)
#define B6  (11.0/84.0)

template <typename T> struct MapT { T A[9]; T b[3]; };  // x -> A x + b

template <typename T>
__device__ inline void map_identity(MapT<T>& m) {
#pragma unroll
  for (int i = 0; i < 9; ++i) m.A[i] = T(0);
  m.A[0] = m.A[4] = m.A[8] = T(1);
  m.b[0] = m.b[1] = m.b[2] = T(0);
}

// out = m2 ∘ m1 (m1 applied first). out must not alias inputs.
template <typename T>
__device__ inline void map_compose(MapT<T>& out, const MapT<T>& m2, const MapT<T>& m1) {
#pragma unroll
  for (int r = 0; r < 3; ++r) {
#pragma unroll
    for (int c = 0; c < 3; ++c)
      out.A[r*3+c] = m2.A[r*3+0]*m1.A[0+c] + m2.A[r*3+1]*m1.A[3+c] + m2.A[r*3+2]*m1.A[6+c];
    out.b[r] = m2.A[r*3+0]*m1.b[0] + m2.A[r*3+1]*m1.b[1] + m2.A[r*3+2]*m1.b[2] + m2.b[r];
  }
}

template <typename T>
__device__ inline void map_apply(const MapT<T>& m, const T x[3], T y[3]) {
#pragma unroll
  for (int r = 0; r < 3; ++r)
    y[r] = m.A[r*3+0]*x[0] + m.A[r*3+1]*x[1] + m.A[r*3+2]*x[2] + m.b[r];
}

template <typename T>
__device__ inline MapT<T> map_shfl_up(const MapT<T>& m, int off) {
  MapT<T> r;
#pragma unroll
  for (int i = 0; i < 9; ++i) r.A[i] = __shfl_up(m.A[i], off, 64);
#pragma unroll
  for (int i = 0; i < 3; ++i) r.b[i] = __shfl_up(m.b[i], off, 64);
  return r;
}

template <typename T, bool RECORD>
__device__ inline void stage_k(const T z[3], const T th[3],
                               T wa, T wb, T g[3], T k[3]) {
  T y0 = fma(wa, z[2], fma(wb, z[1], th[0]));
  T y1 = fma(wa, z[0], fma(wb, z[2], th[1]));
  T y2 = fma(wa, z[1], fma(wb, z[0], th[2]));
  if (RECORD) {
    g[0] = (y0 > T(0)) ? T(1) : T(0);
    g[1] = (y1 > T(0)) ? T(1) : T(0);
    g[2] = (y2 > T(0)) ? T(1) : T(0);
  }
  k[0] = y0 * g[0] - z[0];
  k[1] = y1 * g[1] - z[1];
  k[2] = y2 * g[2] - z[2];
}

template <typename T, bool RECORD>
__device__ inline void dopri_eval(const T v[3], const T th[3], T dt,
                                  T wa, T wb, T G[6][3], T out[3]) {
  T k1[3], k2[3], k3[3], k4[3], k5[3], k6[3], z[3];
  stage_k<T, RECORD>(v, th, wa, wb, G[0], k1);
  const T d21 = dt * T(C21);
#pragma unroll
  for (int c = 0; c < 3; ++c) z[c] = fma(d21, k1[c], v[c]);
  stage_k<T, RECORD>(z, th, wa, wb, G[1], k2);
#pragma unroll
  for (int c = 0; c < 3; ++c) z[c] = fma(dt, fma(T(C31), k1[c], T(C32) * k2[c]), v[c]);
  stage_k<T, RECORD>(z, th, wa, wb, G[2], k3);
#pragma unroll
  for (int c = 0; c < 3; ++c)
    z[c] = fma(dt, fma(T(C41), k1[c], fma(T(C42), k2[c], T(C43) * k3[c])), v[c]);
  stage_k<T, RECORD>(z, th, wa, wb, G[3], k4);
#pragma unroll
  for (int c = 0; c < 3; ++c)
    z[c] = fma(dt, fma(T(C51), k1[c], fma(T(C52), k2[c], fma(T(C53), k3[c], T(C54) * k4[c]))), v[c]);
  stage_k<T, RECORD>(z, th, wa, wb, G[4], k5);
#pragma unroll
  for (int c = 0; c < 3; ++c)
    z[c] = fma(dt, fma(T(C61), k1[c], fma(T(C62), k2[c], fma(T(C63), k3[c], fma(T(C64), k4[c], T(C65) * k5[c])))), v[c]);
  stage_k<T, RECORD>(z, th, wa, wb, G[5], k6);
#pragma unroll
  for (int c = 0; c < 3; ++c)
    out[c] = fma(dt, fma(T(B1), k1[c], fma(T(B3), k3[c], fma(T(B4), k4[c], fma(T(B5), k5[c], T(B6) * k6[c])))), v[c]);
}

template <typename T>
__device__ inline void build_map(const T xo[3], T dt, T wa, T wb,
                                 const T th[3], MapT<T>& m) {
  T G[6][3], dump[3];
  dopri_eval<T, true>(xo, th, dt, wa, wb, G, dump);   // numeric pass -> gates
  const T z3[3] = {T(0), T(0), T(0)};
  dopri_eval<T, false>(z3, th, dt, wa, wb, G, m.b);   // b = F(0) with theta
  T e[3], col[3];
#pragma unroll
  for (int j = 0; j < 3; ++j) {
    e[0] = T(0); e[1] = T(0); e[2] = T(0); e[j] = T(1);
    dopri_eval<T, false>(e, z3, dt, wa, wb, G, col);  // A e_j (theta = 0)
    m.A[0 + j] = col[0];
    m.A[3 + j] = col[1];
    m.A[6 + j] = col[2];
  }
}

// ----------------------------- kernels -------------------------------------

__global__ void k_dts(const float* __restrict__ t, float* __restrict__ dts, int S) {
  int i = blockIdx.x * blockDim.x + threadIdx.x;
  if (i < S) dts[i] = t[i + 1] - t[i];
}

// sequential fp32 RK4 seed at fixed dtc (mask-guess quality only)
__global__ void k_coarse(const float* __restrict__ x0f,
                         const float* __restrict__ le, const float* __restrict__ ld,
                         const float* __restrict__ thf,
                         float* __restrict__ cst, int NC, float dtc) {
  if (threadIdx.x != 0 || blockIdx.x != 0) return;
  const float a = -1.f + expf(le[0]);
  const float b = -1.f - expf(ld[0]);
  const float t0 = thf[0], t1 = thf[1], t2 = thf[2];
  float x = x0f[0], y = x0f[1], z = x0f[2];
  cst[0] = x; cst[1] = y; cst[2] = z;
  const float dt = dtc, dth = 0.5f * dtc, dt6 = dtc * (1.f / 6.f);
#define RHSF(px, py, pz, kx, ky, kz)                      \
  do {                                                    \
    float y0_ = fmaf(a, (pz), fmaf(b, (py), t0));         \
    float y1_ = fmaf(a, (px), fmaf(b, (pz), t1));         \
    float y2_ = fmaf(a, (py), fmaf(b, (px), t2));         \
    (kx) = fmaxf(y0_, 0.f) - (px);                        \
    (ky) = fmaxf(y1_, 0.f) - (py);                        \
    (kz) = fmaxf(y2_, 0.f) - (pz);                        \
  } while (0)
  for (int i = 1; i <= NC; ++i) {
    float k1x,k1y,k1z,k2x,k2y,k2z,k3x,k3y,k3z,k4x,k4y,k4z,zx,zy,zz;
    RHSF(x, y, z, k1x, k1y, k1z);
    zx = fmaf(dth, k1x, x); zy = fmaf(dth, k1y, y); zz = fmaf(dth, k1z, z);
    RHSF(zx, zy, zz, k2x, k2y, k2z);
    zx = fmaf(dth, k2x, x); zy = fmaf(dth, k2y, y); zz = fmaf(dth, k2z, z);
    RHSF(zx, zy, zz, k3x, k3y, k3z);
    zx = fmaf(dt, k3x, x); zy = fmaf(dt, k3y, y); zz = fmaf(dt, k3z, z);
    RHSF(zx, zy, zz, k4x, k4y, k4z);
    x = fmaf(dt6, k1x + 2.f*k2x + 2.f*k3x + k4x, x);
    y = fmaf(dt6, k1y + 2.f*k2y + 2.f*k3y + k4y, y);
    z = fmaf(dt6, k1z + 2.f*k2z + 2.f*k3z + k4z, z);
    cst[3*i] = x; cst[3*i+1] = y; cst[3*i+2] = z;
  }
#undef RHSF
}

// interp seed states (spacing dts_seed) onto the uniform mid grid (spacing dtm)
__global__ void k_interp_s2m(const float* __restrict__ seedst, float* __restrict__ mid,
                             int NMp1, float dtm, float dts_seed, int nseed_states) {
  int n = blockIdx.x * blockDim.x + threadIdx.x;
  if (n >= NMp1) return;
  float u = ((float)n * dtm) / dts_seed;
  int j = (int)u;
  if (j < 0) j = 0;
  if (j > nseed_states - 2) j = nseed_states - 2;
  float f = u - (float)j;
#pragma unroll
  for (int c = 0; c < 3; ++c) {
    float a = seedst[3*j + c], b = seedst[3*(j+1) + c];
    mid[3*n + c] = a + f * (b - a);
  }
}

// one frozen-mask Newton iteration on the uniform mid grid; single block,
// wave-shuffle scan (8 waves x 64 lanes)
#define MIDT 512
template <typename T>
__global__ __launch_bounds__(MIDT) void k_miditer(
    const float* __restrict__ src, float* __restrict__ dst,
    const float* __restrict__ le, const float* __restrict__ ld,
    const float* __restrict__ thf, const float* __restrict__ x0f,
    int NM, double dtm) {
  __shared__ MapT<T> wtot[MIDT / 64];
  const int t = threadIdx.x;
  const int lane = t & 63, wid = t >> 6;
  const T wa = (T)(-1.0 + exp((double)le[0]));
  const T wb = (T)(-1.0 - exp((double)ld[0]));
  const T th[3] = {(T)thf[0], (T)thf[1], (T)thf[2]};
  const T dtmT = (T)dtm;
  const int MCH = (NM + MIDT - 1) / MIDT;

  MapT<T> run, mp, tmp;
  map_identity(run);
  for (int s = 0; s < MCH; ++s) {
    int n = t * MCH + s;
    if (n >= NM) break;
    T xo[3] = {(T)src[3*n], (T)src[3*n+1], (T)src[3*n+2]};
    build_map(xo, dtmT, wa, wb, th, mp);
    map_compose(tmp, mp, run);
    run = tmp;
  }
  // wave inclusive scan (registers)
#pragma unroll
  for (int off = 1; off < 64; off <<= 1) {
    MapT<T> nb = map_shfl_up(run, off);
    MapT<T> comp; map_compose(comp, run, nb);
    if (lane >= off) run = comp;
  }
  if (lane == 63) wtot[wid] = run;
  __syncthreads();
  MapT<T> wpre; map_identity(wpre);
  for (int w = 0; w < wid; ++w) { MapT<T> t2; map_compose(t2, wtot[w], wpre); wpre = t2; }
  // exclusive prefix for this thread = (wave-exclusive of run) ∘ wpre
  MapT<T> excl = map_shfl_up(run, 1);
  if (lane == 0) map_identity(excl);
  MapT<T> P; map_compose(P, excl, wpre);

  const T x0d[3] = {(T)x0f[0], (T)x0f[1], (T)x0f[2]};
  T x[3], xn[3];
  map_apply(P, x0d, x);
  if (t == 0) { dst[0] = x0f[0]; dst[1] = x0f[1]; dst[2] = x0f[2]; }
  for (int s = 0; s < MCH; ++s) {
    int n = t * MCH + s;
    if (n >= NM) break;
    T xo[3] = {(T)src[3*n], (T)src[3*n+1], (T)src[3*n+2]};
    build_map(xo, dtmT, wa, wb, th, mp);
    map_apply(mp, x, xn);
    x[0] = xn[0]; x[1] = xn[1]; x[2] = xn[2];
    dst[3*(n+1)]   = (float)x[0];
    dst[3*(n+1)+1] = (float)x[1];
    dst[3*(n+1)+2] = (float)x[2];
  }
}

// interp mid states (uniform dtm) onto the fine t_eval grid -> guess
__global__ void k_interp_m2f(const float* __restrict__ t_eval, const float* __restrict__ mid,
                             float* __restrict__ guess, int T, float dtm, int nstates) {
  int n = blockIdx.x * blockDim.x + threadIdx.x;
  if (n >= T) return;
  float u = t_eval[n] / dtm;
  int j = (int)u;
  if (j < 0) j = 0;
  if (j > nstates - 2) j = nstates - 2;
  float f = u - (float)j;
#pragma unroll
  for (int c = 0; c < 3; ++c) {
    float a = mid[3*j + c], b = mid[3*(j+1) + c];
    guess[3*n + c] = a + f * (b - a);
  }
}

// ------------------------- fine level (3 kernels) ---------------------------

#define FT 256      // threads per upscan/apply block (4 waves)
#define FT_LOG2 8
#define FCH 8       // fine steps per group
#define BT 512      // bscan threads

// build group maps + wave-shuffle block scan; emit per-thread exclusive
// (within-block) prefixes and block totals
template <typename T>
__global__ __launch_bounds__(FT) void k_upscan(
    const float* __restrict__ src, const float* __restrict__ dts,
    const float* __restrict__ le, const float* __restrict__ ld,
    const float* __restrict__ thf,
    MapT<T>* __restrict__ lpre, MapT<T>* __restrict__ btot, int S, int NG1) {
  __shared__ MapT<T> wtot[FT / 64];
  const int t = threadIdx.x;
  const int lane = t & 63, wid = t >> 6;
  const int g = blockIdx.x * FT + t;
  const T wa = (T)(-1.0 + exp((double)le[0]));
  const T wb = (T)(-1.0 - exp((double)ld[0]));
  const T th[3] = {(T)thf[0], (T)thf[1], (T)thf[2]};

  MapT<T> run, mp, tmp;
  map_identity(run);
  if (g < NG1) {
    for (int s = 0; s < FCH; ++s) {
      int n = g * FCH + s;
      if (n >= S) break;
      T xo[3] = {(T)src[3*n], (T)src[3*n+1], (T)src[3*n+2]};
      build_map(xo, (T)dts[n], wa, wb, th, mp);
      map_compose(tmp, mp, run);
      run = tmp;
    }
  }
  // wave inclusive scan (registers)
#pragma unroll
  for (int off = 1; off < 64; off <<= 1) {
    MapT<T> nb = map_shfl_up(run, off);
    MapT<T> comp; map_compose(comp, run, nb);
    if (lane >= off) run = comp;
  }
  if (lane == 63) wtot[wid] = run;
  __syncthreads();
  MapT<T> wpre; map_identity(wpre);
  for (int w = 0; w < wid; ++w) { MapT<T> t2; map_compose(t2, wtot[w], wpre); wpre = t2; }

  MapT<T> excl = map_shfl_up(run, 1);
  if (lane == 0) map_identity(excl);
  MapT<T> P; map_compose(P, excl, wpre);   // block-exclusive prefix for thread
  lpre[g] = P;
  if (t == FT - 1) { MapT<T> bt; map_compose(bt, run, wpre); btot[blockIdx.x] = bt; }
}

// scan the block totals (NB <= BT); emit exclusive block prefixes
template <typename T>
__global__ __launch_bounds__(BT) void k_bscan(const MapT<T>* __restrict__ btot,
                                              MapT<T>* __restrict__ bpre, int NB) {
  __shared__ MapT<T> wtot[BT / 64];
  const int t = threadIdx.x;
  const int lane = t & 63, wid = t >> 6;
  MapT<T> run;
  if (t < NB) run = btot[t]; else map_identity(run);
#pragma unroll
  for (int off = 1; off < 64; off <<= 1) {
    MapT<T> nb = map_shfl_up(run, off);
    MapT<T> comp; map_compose(comp, run, nb);
    if (lane >= off) run = comp;
  }
  if (lane == 63) wtot[wid] = run;
  __syncthreads();
  MapT<T> wpre; map_identity(wpre);
  for (int w = 0; w < wid; ++w) { MapT<T> t2; map_compose(t2, wtot[w], wpre); wpre = t2; }
  MapT<T> excl = map_shfl_up(run, 1);
  if (lane == 0) map_identity(excl);
  if (t < NB) { MapT<T> P; map_compose(P, excl, wpre); bpre[t] = P; }
}

// compose global prefix, rebuild per-step maps, emit fine states
template <typename T>
__global__ __launch_bounds__(FT) void k_apply2(
    const float* __restrict__ src, float* __restrict__ dst,
    const float* __restrict__ dts,
    const MapT<T>* __restrict__ lpre, const MapT<T>* __restrict__ bpre,
    const float* __restrict__ le, const float* __restrict__ ld,
    const float* __restrict__ thf, const float* __restrict__ x0f, int S, int NG1) {
  const int g = blockIdx.x * blockDim.x + threadIdx.x;
  if (g >= NG1) return;
  const T wa = (T)(-1.0 + exp((double)le[0]));
  const T wb = (T)(-1.0 - exp((double)ld[0]));
  const T th[3] = {(T)thf[0], (T)thf[1], (T)thf[2]};
  const T x0d[3] = {(T)x0f[0], (T)x0f[1], (T)x0f[2]};

  MapT<T> P;
  map_compose(P, lpre[g], bpre[g >> FT_LOG2]);  // block prefix applied first
  T x[3], xn[3];
  map_apply(P, x0d, x);
  if (g == 0) { dst[0] = x0f[0]; dst[1] = x0f[1]; dst[2] = x0f[2]; }
  MapT<T> mp;
  for (int s = 0; s < FCH; ++s) {
    int n = g * FCH + s;
    if (n >= S) break;
    T xo[3] = {(T)src[3*n], (T)src[3*n+1], (T)src[3*n+2]};
    build_map(xo, (T)dts[n], wa, wb, th, mp);
    map_apply(mp, x, xn);
    x[0] = xn[0]; x[1] = xn[1]; x[2] = xn[2];
    dst[3*(n+1)]   = (float)x[0];
    dst[3*(n+1)+1] = (float)x[1];
    dst[3*(n+1)+2] = (float)x[2];
  }
}

__global__ void k_readout(const float* __restrict__ traj, const float* __restrict__ w,
                          const float* __restrict__ bvec, float* __restrict__ pred, int T) {
  const float w00=w[0],w01=w[1],w02=w[2];
  const float w10=w[3],w11=w[4],w12=w[5];
  const float w20=w[6],w21=w[7],w22=w[8];
  const float b0=bvec[0], b1=bvec[1], b2=bvec[2];
  for (int i = blockIdx.x * blockDim.x + threadIdx.x; i < T;
       i += gridDim.x * blockDim.x) {
    const float x0 = traj[3*i], x1 = traj[3*i+1], x2 = traj[3*i+2];
    pred[3*i]   = fmaf(w00,x0, fmaf(w01,x1, fmaf(w02,x2, b0)));
    pred[3*i+1] = fmaf(w10,x0, fmaf(w11,x1, fmaf(w12,x2, b1)));
    pred[3*i+2] = fmaf(w20,x0, fmaf(w21,x1, fmaf(w22,x2, b2)));
  }
}

// ----------------------------- launcher ------------------------------------

extern "C" void kernel_launch(void* const* d_in, const int* in_sizes, int n_in,
                              void* d_out, int out_size, void* d_ws, size_t ws_size,
                              hipStream_t stream) {
  const float* t_eval    = (const float*)d_in[0];
  const float* x0        = (const float*)d_in[1];
  const float* log_eps   = (const float*)d_in[2];
  const float* log_delta = (const float*)d_in[3];
  const float* theta     = (const float*)d_in[4];
  const float* readout_w = (const float*)d_in[5];
  const float* readout_b = (const float*)d_in[6];

  const int T   = in_sizes[0];
  const int S   = T - 1;
  const int NG1 = (S + FCH - 1) / FCH;          // 125000 fine groups
  const int NB  = (NG1 + FT - 1) / FT;          // 489 fine blocks (<= BT)

  const float  DTS_SEED = 0.45f;
  const int    NSEED    = (int)(((double)S * 1e-3) / (double)DTS_SEED) + 2;  // 2224
  const double DTM      = 0.064;
  const int    NM       = (int)(((double)S * 1e-3) / DTM) + 1;               // 15625

  float* trajh = (float*)d_out;
  float* predh = trajh + (size_t)3 * T;

  // workspace sized for the fp64 (largest) Map variants; fp32 reuses same slots
  char* w = (char*)d_ws;
  float* dts    = (float*)w;  w += (((size_t)S * 4) + 255) & ~(size_t)255;
  float* seedst = (float*)w;  w += (((size_t)3 * (NSEED + 1) * 4) + 255) & ~(size_t)255;
  float* midA   = (float*)w;  w += (((size_t)3 * (NM + 1) * 4) + 255) & ~(size_t)255;
  float* midB   = (float*)w;  w += (((size_t)3 * (NM + 1) * 4) + 255) & ~(size_t)255;
  void* lpre_v  = (void*)w;   w += (((size_t)NB * FT * sizeof(MapT<double>)) + 255) & ~(size_t)255;
  void* btot_v  = (void*)w;   w += (((size_t)BT * sizeof(MapT<double>)) + 255) & ~(size_t)255;
  void* bpre_v  = (void*)w;

  k_dts<<<(S + 255) / 256, 256, 0, stream>>>(t_eval, dts, S);
  k_coarse<<<1, 64, 0, stream>>>(x0, log_eps, log_delta, theta, seedst, NSEED, DTS_SEED);
  k_interp_s2m<<<(NM + 1 + 255) / 256, 256, 0, stream>>>(seedst, midA, NM + 1,
                                                         (float)DTM, DTS_SEED, NSEED + 1);
  // 8 fp32 mid Newton iterations (even count: final lands back in midA)
  for (int it = 0; it < 8; ++it) {
    const float* s = (it % 2 == 0) ? midA : midB;
    float*       d = (it % 2 == 0) ? midB : midA;
    k_miditer<float><<<1, MIDT, 0, stream>>>(s, d, log_eps, log_delta, theta, x0, NM, DTM);
  }

  // guess -> predh; fine: it0 fp32 predh->trajh... wait parity:
  // it0 fp32 reads predh writes trajh is wrong landing; use:
  //   interp -> trajh ; it0 fp32 trajh->predh ; it1 fp64 predh->trajh (final)
  k_interp_m2f<<<(T + 255) / 256, 256, 0, stream>>>(t_eval, midA, trajh, T,
                                                    (float)DTM, NM + 1);
  {
    MapT<float>* lpre = (MapT<float>*)lpre_v;
    MapT<float>* btot = (MapT<float>*)btot_v;
    MapT<float>* bpre = (MapT<float>*)bpre_v;
    k_upscan<float><<<NB, FT, 0, stream>>>(trajh, dts, log_eps, log_delta, theta,
                                           lpre, btot, S, NG1);
    k_bscan<float><<<1, BT, 0, stream>>>(btot, bpre, NB);
    k_apply2<float><<<(NG1 + FT - 1) / FT, FT, 0, stream>>>(trajh, predh, dts, lpre, bpre,
                                                            log_eps, log_delta, theta,
                                                            x0, S, NG1);
  }
  {
    MapT<double>* lpre = (MapT<double>*)lpre_v;
    MapT<double>* btot = (MapT<double>*)btot_v;
    MapT<double>* bpre = (MapT<double>*)bpre_v;
    k_upscan<double><<<NB, FT, 0, stream>>>(predh, dts, log_eps, log_delta, theta,
                                            lpre, btot, S, NG1);
    k_bscan<double><<<1, BT, 0, stream>>>(btot, bpre, NB);
    k_apply2<double><<<(NG1 + FT - 1) / FT, FT, 0, stream>>>(predh, trajh, dts, lpre, bpre,
                                                             log_eps, log_delta, theta,
                                                             x0, S, NG1);
  }

  k_readout<<<2048, 256, 0, stream>>>(trajh, readout_w, readout_b, predh, T);
}

// Round 8
// 627.176 us; speedup vs baseline: 508.0779x; 2.6886x over previous
//
#include <hip/hip_runtime.h>
#include <math.h>

// ---------------------------------------------------------------------------
// GCTLN round 8: 2-level scheme; no mid level, no fp64 scan.
//   L0 seed  : serial fp32 RK4, dt=0.45 (2224 steps)  [unchanged]
//   L1 fine  : 4x fp32 frozen-mask affine scan iters (upscan/bscan/apply2)
//   polish   : fp64 re-shooting — 8 plain dopri5 steps per thread from the
//              converged fp32 guess (no scan; start error ~1e-6 propagates
//              <=8 steps). Replaces the expensive fp64 scan iteration.
// d_out layout: [traj 3T][pred 3T]; guess ping-pongs between halves.
// ---------------------------------------------------------------------------

#define C21 (1.0/5.0)
#define C31 (3.0/40.0)
#define C32 (9.0/40.0)
#define C41 (44.0/45.0)
#define C42 (-56.0/15.0)
#define C43 (32.0/9.0)
#define C51 (19372.0/6561.0)
#define C52 (-25360.0/2187.0)
#define C53 (64448.0/6561.0)
#define C54 (-212.0/729.0)
#define C61 (9017.0/3168.0)
#define C62 (-355.0/33.0)
#define C63 (46732.0/5247.0)
#define C64 (49.0/176.0)
#define C65 (-5103.0/18656.0)
#define B1  (35.0/384.0)
#define B3  (500.0/1113.0)
#define B4  (125.0/192.0)
#define B5  (-2187.0/6784.0)
#define B6  (11.0/84.0)

template <typename T> struct MapT { T A[9]; T b[3]; };  // x -> A x + b

template <typename T>
__device__ inline void map_identity(MapT<T>& m) {
#pragma unroll
  for (int i = 0; i < 9; ++i) m.A[i] = T(0);
  m.A[0] = m.A[4] = m.A[8] = T(1);
  m.b[0] = m.b[1] = m.b[2] = T(0);
}

// out = m2 ∘ m1 (m1 applied first). out must not alias inputs.
template <typename T>
__device__ inline void map_compose(MapT<T>& out, const MapT<T>& m2, const MapT<T>& m1) {
#pragma unroll
  for (int r = 0; r < 3; ++r) {
#pragma unroll
    for (int c = 0; c < 3; ++c)
      out.A[r*3+c] = m2.A[r*3+0]*m1.A[0+c] + m2.A[r*3+1]*m1.A[3+c] + m2.A[r*3+2]*m1.A[6+c];
    out.b[r] = m2.A[r*3+0]*m1.b[0] + m2.A[r*3+1]*m1.b[1] + m2.A[r*3+2]*m1.b[2] + m2.b[r];
  }
}

template <typename T>
__device__ inline void map_apply(const MapT<T>& m, const T x[3], T y[3]) {
#pragma unroll
  for (int r = 0; r < 3; ++r)
    y[r] = m.A[r*3+0]*x[0] + m.A[r*3+1]*x[1] + m.A[r*3+2]*x[2] + m.b[r];
}

template <typename T>
__device__ inline MapT<T> map_shfl_up(const MapT<T>& m, int off) {
  MapT<T> r;
#pragma unroll
  for (int i = 0; i < 9; ++i) r.A[i] = __shfl_up(m.A[i], off, 64);
#pragma unroll
  for (int i = 0; i < 3; ++i) r.b[i] = __shfl_up(m.b[i], off, 64);
  return r;
}

template <typename T, bool RECORD>
__device__ inline void stage_k(const T z[3], const T th[3],
                               T wa, T wb, T g[3], T k[3]) {
  T y0 = fma(wa, z[2], fma(wb, z[1], th[0]));
  T y1 = fma(wa, z[0], fma(wb, z[2], th[1]));
  T y2 = fma(wa, z[1], fma(wb, z[0], th[2]));
  if (RECORD) {
    g[0] = (y0 > T(0)) ? T(1) : T(0);
    g[1] = (y1 > T(0)) ? T(1) : T(0);
    g[2] = (y2 > T(0)) ? T(1) : T(0);
  }
  k[0] = y0 * g[0] - z[0];
  k[1] = y1 * g[1] - z[1];
  k[2] = y2 * g[2] - z[2];
}

// With RECORD=true this is exactly a plain dopri5 step (gates = relu masks
// computed from the actual stage values).
template <typename T, bool RECORD>
__device__ inline void dopri_eval(const T v[3], const T th[3], T dt,
                                  T wa, T wb, T G[6][3], T out[3]) {
  T k1[3], k2[3], k3[3], k4[3], k5[3], k6[3], z[3];
  stage_k<T, RECORD>(v, th, wa, wb, G[0], k1);
  const T d21 = dt * T(C21);
#pragma unroll
  for (int c = 0; c < 3; ++c) z[c] = fma(d21, k1[c], v[c]);
  stage_k<T, RECORD>(z, th, wa, wb, G[1], k2);
#pragma unroll
  for (int c = 0; c < 3; ++c) z[c] = fma(dt, fma(T(C31), k1[c], T(C32) * k2[c]), v[c]);
  stage_k<T, RECORD>(z, th, wa, wb, G[2], k3);
#pragma unroll
  for (int c = 0; c < 3; ++c)
    z[c] = fma(dt, fma(T(C41), k1[c], fma(T(C42), k2[c], T(C43) * k3[c])), v[c]);
  stage_k<T, RECORD>(z, th, wa, wb, G[3], k4);
#pragma unroll
  for (int c = 0; c < 3; ++c)
    z[c] = fma(dt, fma(T(C51), k1[c], fma(T(C52), k2[c], fma(T(C53), k3[c], T(C54) * k4[c]))), v[c]);
  stage_k<T, RECORD>(z, th, wa, wb, G[4], k5);
#pragma unroll
  for (int c = 0; c < 3; ++c)
    z[c] = fma(dt, fma(T(C61), k1[c], fma(T(C62), k2[c], fma(T(C63), k3[c], fma(T(C64), k4[c], T(C65) * k5[c])))), v[c]);
  stage_k<T, RECORD>(z, th, wa, wb, G[5], k6);
#pragma unroll
  for (int c = 0; c < 3; ++c)
    out[c] = fma(dt, fma(T(B1), k1[c], fma(T(B3), k3[c], fma(T(B4), k4[c], fma(T(B5), k5[c], T(B6) * k6[c])))), v[c]);
}

template <typename T>
__device__ inline void build_map(const T xo[3], T dt, T wa, T wb,
                                 const T th[3], MapT<T>& m) {
  T G[6][3], dump[3];
  dopri_eval<T, true>(xo, th, dt, wa, wb, G, dump);   // numeric pass -> gates
  const T z3[3] = {T(0), T(0), T(0)};
  dopri_eval<T, false>(z3, th, dt, wa, wb, G, m.b);   // b = F(0) with theta
  T e[3], col[3];
#pragma unroll
  for (int j = 0; j < 3; ++j) {
    e[0] = T(0); e[1] = T(0); e[2] = T(0); e[j] = T(1);
    dopri_eval<T, false>(e, z3, dt, wa, wb, G, col);  // A e_j (theta = 0)
    m.A[0 + j] = col[0];
    m.A[3 + j] = col[1];
    m.A[6 + j] = col[2];
  }
}

// ----------------------------- kernels -------------------------------------

__global__ void k_dts(const float* __restrict__ t, float* __restrict__ dts, int S) {
  int i = blockIdx.x * blockDim.x + threadIdx.x;
  if (i < S) dts[i] = t[i + 1] - t[i];
}

// sequential fp32 RK4 seed at fixed dtc (mask-guess quality only)
__global__ void k_coarse(const float* __restrict__ x0f,
                         const float* __restrict__ le, const float* __restrict__ ld,
                         const float* __restrict__ thf,
                         float* __restrict__ cst, int NC, float dtc) {
  if (threadIdx.x != 0 || blockIdx.x != 0) return;
  const float a = -1.f + expf(le[0]);
  const float b = -1.f - expf(ld[0]);
  const float t0 = thf[0], t1 = thf[1], t2 = thf[2];
  float x = x0f[0], y = x0f[1], z = x0f[2];
  cst[0] = x; cst[1] = y; cst[2] = z;
  const float dt = dtc, dth = 0.5f * dtc, dt6 = dtc * (1.f / 6.f);
#define RHSF(px, py, pz, kx, ky, kz)                      \
  do {                                                    \
    float y0_ = fmaf(a, (pz), fmaf(b, (py), t0));         \
    float y1_ = fmaf(a, (px), fmaf(b, (pz), t1));         \
    float y2_ = fmaf(a, (py), fmaf(b, (px), t2));         \
    (kx) = fmaxf(y0_, 0.f) - (px);                        \
    (ky) = fmaxf(y1_, 0.f) - (py);                        \
    (kz) = fmaxf(y2_, 0.f) - (pz);                        \
  } while (0)
  for (int i = 1; i <= NC; ++i) {
    float k1x,k1y,k1z,k2x,k2y,k2z,k3x,k3y,k3z,k4x,k4y,k4z,zx,zy,zz;
    RHSF(x, y, z, k1x, k1y, k1z);
    zx = fmaf(dth, k1x, x); zy = fmaf(dth, k1y, y); zz = fmaf(dth, k1z, z);
    RHSF(zx, zy, zz, k2x, k2y, k2z);
    zx = fmaf(dth, k2x, x); zy = fmaf(dth, k2y, y); zz = fmaf(dth, k2z, z);
    RHSF(zx, zy, zz, k3x, k3y, k3z);
    zx = fmaf(dt, k3x, x); zy = fmaf(dt, k3y, y); zz = fmaf(dt, k3z, z);
    RHSF(zx, zy, zz, k4x, k4y, k4z);
    x = fmaf(dt6, k1x + 2.f*k2x + 2.f*k3x + k4x, x);
    y = fmaf(dt6, k1y + 2.f*k2y + 2.f*k3y + k4y, y);
    z = fmaf(dt6, k1z + 2.f*k2z + 2.f*k3z + k4z, z);
    cst[3*i] = x; cst[3*i+1] = y; cst[3*i+2] = z;
  }
#undef RHSF
}

// interp states on a uniform grid (spacing h, nstates points) onto t_eval
__global__ void k_interp(const float* __restrict__ t_eval, const float* __restrict__ st,
                         float* __restrict__ out, int T, float h, int nstates) {
  int n = blockIdx.x * blockDim.x + threadIdx.x;
  if (n >= T) return;
  float u = t_eval[n] / h;
  int j = (int)u;
  if (j < 0) j = 0;
  if (j > nstates - 2) j = nstates - 2;
  float f = u - (float)j;
#pragma unroll
  for (int c = 0; c < 3; ++c) {
    float a = st[3*j + c], b = st[3*(j+1) + c];
    out[3*n + c] = a + f * (b - a);
  }
}

// ------------------------- fine level (3 kernels) ---------------------------

#define FT 256      // threads per upscan/apply block (4 waves)
#define FT_LOG2 8
#define FCH 8       // fine steps per group
#define BT 512      // bscan threads

template <typename T>
__global__ __launch_bounds__(FT) void k_upscan(
    const float* __restrict__ src, const float* __restrict__ dts,
    const float* __restrict__ le, const float* __restrict__ ld,
    const float* __restrict__ thf,
    MapT<T>* __restrict__ lpre, MapT<T>* __restrict__ btot, int S, int NG1) {
  __shared__ MapT<T> wtot[FT / 64];
  const int t = threadIdx.x;
  const int lane = t & 63, wid = t >> 6;
  const int g = blockIdx.x * FT + t;
  const T wa = (T)(-1.0 + exp((double)le[0]));
  const T wb = (T)(-1.0 - exp((double)ld[0]));
  const T th[3] = {(T)thf[0], (T)thf[1], (T)thf[2]};

  MapT<T> run, mp, tmp;
  map_identity(run);
  if (g < NG1) {
    for (int s = 0; s < FCH; ++s) {
      int n = g * FCH + s;
      if (n >= S) break;
      T xo[3] = {(T)src[3*n], (T)src[3*n+1], (T)src[3*n+2]};
      build_map(xo, (T)dts[n], wa, wb, th, mp);
      map_compose(tmp, mp, run);
      run = tmp;
    }
  }
  // wave inclusive scan (registers)
#pragma unroll
  for (int off = 1; off < 64; off <<= 1) {
    MapT<T> nb = map_shfl_up(run, off);
    MapT<T> comp; map_compose(comp, run, nb);
    if (lane >= off) run = comp;
  }
  if (lane == 63) wtot[wid] = run;
  __syncthreads();
  MapT<T> wpre; map_identity(wpre);
  for (int w = 0; w < wid; ++w) { MapT<T> t2; map_compose(t2, wtot[w], wpre); wpre = t2; }

  MapT<T> excl = map_shfl_up(run, 1);
  if (lane == 0) map_identity(excl);
  MapT<T> P; map_compose(P, excl, wpre);   // block-exclusive prefix for thread
  lpre[g] = P;
  if (t == FT - 1) { MapT<T> bt; map_compose(bt, run, wpre); btot[blockIdx.x] = bt; }
}

template <typename T>
__global__ __launch_bounds__(BT) void k_bscan(const MapT<T>* __restrict__ btot,
                                              MapT<T>* __restrict__ bpre, int NB) {
  __shared__ MapT<T> wtot[BT / 64];
  const int t = threadIdx.x;
  const int lane = t & 63, wid = t >> 6;
  MapT<T> run;
  if (t < NB) run = btot[t]; else map_identity(run);
#pragma unroll
  for (int off = 1; off < 64; off <<= 1) {
    MapT<T> nb = map_shfl_up(run, off);
    MapT<T> comp; map_compose(comp, run, nb);
    if (lane >= off) run = comp;
  }
  if (lane == 63) wtot[wid] = run;
  __syncthreads();
  MapT<T> wpre; map_identity(wpre);
  for (int w = 0; w < wid; ++w) { MapT<T> t2; map_compose(t2, wtot[w], wpre); wpre = t2; }
  MapT<T> excl = map_shfl_up(run, 1);
  if (lane == 0) map_identity(excl);
  if (t < NB) { MapT<T> P; map_compose(P, excl, wpre); bpre[t] = P; }
}

template <typename T>
__global__ __launch_bounds__(FT) void k_apply2(
    const float* __restrict__ src, float* __restrict__ dst,
    const float* __restrict__ dts,
    const MapT<T>* __restrict__ lpre, const MapT<T>* __restrict__ bpre,
    const float* __restrict__ le, const float* __restrict__ ld,
    const float* __restrict__ thf, const float* __restrict__ x0f, int S, int NG1) {
  const int g = blockIdx.x * blockDim.x + threadIdx.x;
  if (g >= NG1) return;
  const T wa = (T)(-1.0 + exp((double)le[0]));
  const T wb = (T)(-1.0 - exp((double)ld[0]));
  const T th[3] = {(T)thf[0], (T)thf[1], (T)thf[2]};
  const T x0d[3] = {(T)x0f[0], (T)x0f[1], (T)x0f[2]};

  MapT<T> P;
  map_compose(P, lpre[g], bpre[g >> FT_LOG2]);  // block prefix applied first
  T x[3], xn[3];
  map_apply(P, x0d, x);
  if (g == 0) { dst[0] = x0f[0]; dst[1] = x0f[1]; dst[2] = x0f[2]; }
  MapT<T> mp;
  for (int s = 0; s < FCH; ++s) {
    int n = g * FCH + s;
    if (n >= S) break;
    T xo[3] = {(T)src[3*n], (T)src[3*n+1], (T)src[3*n+2]};
    build_map(xo, (T)dts[n], wa, wb, th, mp);
    map_apply(mp, x, xn);
    x[0] = xn[0]; x[1] = xn[1]; x[2] = xn[2];
    dst[3*(n+1)]   = (float)x[0];
    dst[3*(n+1)+1] = (float)x[1];
    dst[3*(n+1)+2] = (float)x[2];
  }
}

// fp64 re-shooting polish: 8 plain dopri5 steps per thread from the fp32
// guess at the group start. No scan, no maps.
__global__ __launch_bounds__(256) void k_polish(
    const float* __restrict__ src, float* __restrict__ dst,
    const float* __restrict__ dts,
    const float* __restrict__ le, const float* __restrict__ ld,
    const float* __restrict__ thf, const float* __restrict__ x0f, int S, int NG1) {
  const int g = blockIdx.x * blockDim.x + threadIdx.x;
  if (g >= NG1) return;
  const double wa = -1.0 + exp((double)le[0]);
  const double wb = -1.0 - exp((double)ld[0]);
  const double th[3] = {(double)thf[0], (double)thf[1], (double)thf[2]};
  const int n0 = g * FCH;
  double x[3];
  if (g == 0) {
    x[0] = (double)x0f[0]; x[1] = (double)x0f[1]; x[2] = (double)x0f[2];
    dst[0] = x0f[0]; dst[1] = x0f[1]; dst[2] = x0f[2];
  } else {
    x[0] = (double)src[3*n0]; x[1] = (double)src[3*n0+1]; x[2] = (double)src[3*n0+2];
  }
  double G[6][3], xn[3];
  for (int s = 0; s < FCH; ++s) {
    int n = n0 + s;
    if (n >= S) break;
    dopri_eval<double, true>(x, th, (double)dts[n], wa, wb, G, xn);
    x[0] = xn[0]; x[1] = xn[1]; x[2] = xn[2];
    dst[3*(n+1)]   = (float)x[0];
    dst[3*(n+1)+1] = (float)x[1];
    dst[3*(n+1)+2] = (float)x[2];
  }
}

__global__ void k_readout(const float* __restrict__ traj, const float* __restrict__ w,
                          const float* __restrict__ bvec, float* __restrict__ pred, int T) {
  const float w00=w[0],w01=w[1],w02=w[2];
  const float w10=w[3],w11=w[4],w12=w[5];
  const float w20=w[6],w21=w[7],w22=w[8];
  const float b0=bvec[0], b1=bvec[1], b2=bvec[2];
  for (int i = blockIdx.x * blockDim.x + threadIdx.x; i < T;
       i += gridDim.x * blockDim.x) {
    const float x0 = traj[3*i], x1 = traj[3*i+1], x2 = traj[3*i+2];
    pred[3*i]   = fmaf(w00,x0, fmaf(w01,x1, fmaf(w02,x2, b0)));
    pred[3*i+1] = fmaf(w10,x0, fmaf(w11,x1, fmaf(w12,x2, b1)));
    pred[3*i+2] = fmaf(w20,x0, fmaf(w21,x1, fmaf(w22,x2, b2)));
  }
}

// ----------------------------- launcher ------------------------------------

extern "C" void kernel_launch(void* const* d_in, const int* in_sizes, int n_in,
                              void* d_out, int out_size, void* d_ws, size_t ws_size,
                              hipStream_t stream) {
  const float* t_eval    = (const float*)d_in[0];
  const float* x0        = (const float*)d_in[1];
  const float* log_eps   = (const float*)d_in[2];
  const float* log_delta = (const float*)d_in[3];
  const float* theta     = (const float*)d_in[4];
  const float* readout_w = (const float*)d_in[5];
  const float* readout_b = (const float*)d_in[6];

  const int T   = in_sizes[0];
  const int S   = T - 1;
  const int NG1 = (S + FCH - 1) / FCH;          // 125000 fine groups
  const int NB  = (NG1 + FT - 1) / FT;          // 489 fine blocks (<= BT)

  const float  DTS_SEED = 0.45f;
  const int    NSEED    = (int)(((double)S * 1e-3) / (double)DTS_SEED) + 2;  // 2224

  float* trajh = (float*)d_out;
  float* predh = trajh + (size_t)3 * T;

  char* w = (char*)d_ws;
  float* dts    = (float*)w;  w += (((size_t)S * 4) + 255) & ~(size_t)255;
  float* seedst = (float*)w;  w += (((size_t)3 * (NSEED + 1) * 4) + 255) & ~(size_t)255;
  MapT<float>* lpre = (MapT<float>*)w; w += (((size_t)NB * FT * sizeof(MapT<float>)) + 255) & ~(size_t)255;
  MapT<float>* btot = (MapT<float>*)w; w += (((size_t)BT * sizeof(MapT<float>)) + 255) & ~(size_t)255;
  MapT<float>* bpre = (MapT<float>*)w;

  k_dts<<<(S + 255) / 256, 256, 0, stream>>>(t_eval, dts, S);
  k_coarse<<<1, 64, 0, stream>>>(x0, log_eps, log_delta, theta, seedst, NSEED, DTS_SEED);
  // seed -> fine-grid guess (into predh)
  k_interp<<<(T + 255) / 256, 256, 0, stream>>>(t_eval, seedst, predh, T,
                                                DTS_SEED, NSEED + 1);

  // 4 fp32 fine Newton iterations (even count: final guess lands in predh)
  for (int it = 0; it < 4; ++it) {
    const float* src = (it % 2 == 0) ? predh : trajh;
    float*       dst = (it % 2 == 0) ? trajh : predh;
    k_upscan<float><<<NB, FT, 0, stream>>>(src, dts, log_eps, log_delta, theta,
                                           lpre, btot, S, NG1);
    k_bscan<float><<<1, BT, 0, stream>>>(btot, bpre, NB);
    k_apply2<float><<<(NG1 + FT - 1) / FT, FT, 0, stream>>>(src, dst, dts, lpre, bpre,
                                                            log_eps, log_delta, theta,
                                                            x0, S, NG1);
  }

  // fp64 re-shooting polish: predh (guess) -> trajh (final)
  k_polish<<<(NG1 + 255) / 256, 256, 0, stream>>>(predh, trajh, dts, log_eps,
                                                  log_delta, theta, x0, S, NG1);

  k_readout<<<2048, 256, 0, stream>>>(trajh, readout_w, readout_b, predh, T);
}